// Round 6
// baseline (605.417 us; speedup 1.0000x reference)
//
#include <hip/hip_runtime.h>
#include <hip/hip_bf16.h>

typedef __attribute__((ext_vector_type(8))) short short8;
typedef __attribute__((ext_vector_type(4))) float floatx4;

__device__ __forceinline__ float lrelu(float a){ return a > 0.f ? a : 0.2f * a; }
__device__ __forceinline__ float bflo(unsigned u){ return __uint_as_float(u << 16); }
__device__ __forceinline__ float bfhi(unsigned u){ return __uint_as_float(u & 0xffff0000u); }
__device__ __forceinline__ unsigned short f2bf(float f){
  __hip_bfloat16 h = __float2bfloat16(f);
  return *reinterpret_cast<unsigned short*>(&h);
}
__device__ __forceinline__ float dot4(float4 a, float4 b){
  return a.x*b.x + a.y*b.y + a.z*b.z + a.w*b.w;
}

// ---------------- fused prep + count (dst AND src degrees) ----------------
// blocks [0, CB): per-edge slot within dst bucket + src bucket (atomics)
// block CB+0 -> we1/we2 dots ; CB+1..CB+128 -> W1t ; CB+129..CB+192 -> W2t
__global__ __launch_bounds__(256) void k_prep(const int* __restrict__ src, const int* __restrict__ dst,
                       int* __restrict__ degi, int* __restrict__ sdeg,
                       int* __restrict__ eslot, int* __restrict__ sslot, int E, int CB,
                       const float* __restrict__ We1, const float* __restrict__ ae1,
                       const float* __restrict__ We2, const float* __restrict__ ae2,
                       float* __restrict__ we1, float* __restrict__ we2,
                       const float* __restrict__ W1, unsigned short* __restrict__ W1t,
                       const float* __restrict__ W2, unsigned short* __restrict__ W2t) {
  int t = threadIdx.x;
  if (blockIdx.x < (unsigned)CB) {
    int e = blockIdx.x * 256 + t;
    if (e < E) {
      eslot[e] = atomicAdd(degi + dst[e], 1);
      sslot[e] = atomicAdd(sdeg + src[e], 1);
    }
    return;
  }
  int b = blockIdx.x - CB;
  if (b == 0) {
    if (t >= 64) return;
    float s1 = 0.f, s2 = 0.f;
    if (t < 60) {
      const float4* r1 = reinterpret_cast<const float4*>(We1 + t * 128);
      const float4* r2 = reinterpret_cast<const float4*>(We2 + t * 128);
      const float4* a1 = reinterpret_cast<const float4*>(ae1);
      const float4* a2 = reinterpret_cast<const float4*>(ae2);
      for (int i = 0; i < 32; ++i) {
        float4 x1 = r1[i], y1 = a1[i];
        float4 x2 = r2[i], y2 = a2[i];
        s1 += x1.x*y1.x + x1.y*y1.y + x1.z*y1.z + x1.w*y1.w;
        s2 += x2.x*y2.x + x2.y*y2.y + x2.z*y2.z + x2.w*y2.w;
      }
    }
    we1[t] = s1; we2[t] = s2;
  } else if (b <= 128) {
    int idx = (b - 1) * 256 + t;            // K=256: 32768 elems
    int k = idx >> 7, n = idx & 127;
    W1t[(size_t)n * 256 + k] = f2bf(W1[idx]);
  } else {
    int idx = (b - 129) * 256 + t;          // K=128: 16384 elems
    int k = idx >> 7, n = idx & 127;
    W2t[(size_t)n * 128 + k] = f2bf(W2[idx]);
  }
}

// single-block exclusive scan body (1024 threads); wave shfl_up scans, 2 barriers
__device__ __forceinline__ void scan_body(const int* __restrict__ degi, int* __restrict__ rowptr,
                                          int N, int E) {
  __shared__ int wsums[16];
  int t = threadIdx.x;
  int wave = t >> 6, lane = t & 63;
  const int CH = 52;                 // 13 * int4 ; 1024*52 = 53248 >= N
  int lo = t * CH;
  int v[52];
  int s = 0;
  #pragma unroll
  for (int i = 0; i < 13; ++i) {
    int base_i = lo + 4 * i;
    if (base_i + 4 <= N) {
      int4 q = *reinterpret_cast<const int4*>(degi + base_i);
      v[4*i+0] = q.x; v[4*i+1] = q.y; v[4*i+2] = q.z; v[4*i+3] = q.w;
      s += q.x + q.y + q.z + q.w;
    } else {
      #pragma unroll
      for (int j = 0; j < 4; ++j) {
        int idx = base_i + j;
        int x = (idx < N) ? degi[idx] : 0;
        v[4*i+j] = x; s += x;
      }
    }
  }
  int inc = s;
  #pragma unroll
  for (int off = 1; off < 64; off <<= 1) {
    int u = __shfl_up(inc, off);
    if (lane >= off) inc += u;
  }
  if (lane == 63) wsums[wave] = inc;
  __syncthreads();
  if (wave == 0) {
    int ws = (lane < 16) ? wsums[lane] : 0;
    #pragma unroll
    for (int off = 1; off < 16; off <<= 1) {
      int u = __shfl_up(ws, off);
      if (lane >= off) ws += u;
    }
    if (lane < 16) wsums[lane] = ws;
  }
  __syncthreads();
  int base = inc - s + (wave ? wsums[wave - 1] : 0);
  #pragma unroll
  for (int i = 0; i < 13; ++i) {
    int base_i = lo + 4 * i;
    if (base_i + 4 <= N) {
      int4 o;
      o.x = base; base += v[4*i+0];
      o.y = base; base += v[4*i+1];
      o.z = base; base += v[4*i+2];
      o.w = base; base += v[4*i+3];
      *reinterpret_cast<int4*>(rowptr + base_i) = o;
    } else {
      #pragma unroll
      for (int j = 0; j < 4; ++j) {
        int idx = base_i + j;
        if (idx < N) { rowptr[idx] = base; base += v[4*i+j]; }
      }
    }
  }
  if (t == 0) rowptr[N] = E;
}

// ---------------- fused dual scan + streaming e-dot ----------------
// block 0: scan degi->rowptr ; block 1: scan sdeg->srowptr
// blocks 2..: pure stream e-dot, quarter-thread-group per edge
__global__ __launch_bounds__(1024) void k_scanedot(const int* __restrict__ degi, int* __restrict__ rowptr,
                       const int* __restrict__ sdeg, int* __restrict__ srowptr,
                       int N, int E,
                       const float* __restrict__ ef,
                       const float* __restrict__ we1, const float* __restrict__ we2,
                       float2* __restrict__ edgeD, int EDOTB) {
  if (blockIdx.x == 0) { scan_body(degi, rowptr, N, E); return; }
  if (blockIdx.x == 1) { scan_body(sdeg, srowptr, N, E); return; }
  int t = threadIdx.x;
  int sub = t & 3;
  int qw = (int)(blockIdx.x - 2) * 256 + (t >> 2);
  const float4* w1v = reinterpret_cast<const float4*>(we1);
  const float4* w2v = reinterpret_cast<const float4*>(we2);
  float4 wa0 = w1v[sub],     wb0 = w2v[sub];
  float4 wa1 = w1v[sub + 4], wb1 = w2v[sub + 4];
  float4 wa2 = w1v[sub + 8], wb2 = w2v[sub + 8];
  bool has3 = sub < 3;
  float4 wa3 = make_float4(0.f,0.f,0.f,0.f), wb3 = wa3;
  if (has3) { wa3 = w1v[sub + 12]; wb3 = w2v[sub + 12]; }
  const float4* efq = reinterpret_cast<const float4*>(ef);
  int stride = EDOTB * 256;
  for (int e = qw; e < E; e += stride) {
    size_t b = (size_t)e * 15;
    float4 f0 = efq[b + sub];
    float4 f1 = efq[b + sub + 4];
    float4 f2 = efq[b + sub + 8];
    float4 f3 = make_float4(0.f,0.f,0.f,0.f);
    if (has3) f3 = efq[b + sub + 12];
    float d1 = dot4(f0, wa0) + dot4(f1, wa1) + dot4(f2, wa2) + dot4(f3, wa3);
    float d2 = dot4(f0, wb0) + dot4(f1, wb1) + dot4(f2, wb2) + dot4(f3, wb3);
    d1 += __shfl_xor(d1, 1); d1 += __shfl_xor(d1, 2);
    d2 += __shfl_xor(d2, 1); d2 += __shfl_xor(d2, 2);
    if (sub == 0) edgeD[e] = make_float2(d1, d2);
  }
}

// Full-width MFMA GEMM body: one wave computes C[16,128] = A[16,K] @ Bt[128,K]^T.
// Alpha epilogue: full 128-col dot with a_src/a_dst in-wave, direct store (no atomics).
template <int K, bool AFP32>
__device__ __forceinline__ void gemm_body(int wid, int lane,
    const void* __restrict__ Av, const unsigned short* __restrict__ Bt,
    unsigned short* __restrict__ C,
    const float* __restrict__ a_src, const float* __restrict__ a_dst,
    float* __restrict__ alps, float* __restrict__ alpd, int M) {
  int mt = wid;
  if (mt * 16 >= M) return;
  int r = lane & 15, quad = lane >> 4;
  int m = mt * 16 + r;
  floatx4 acc[8] = {};
  for (int k0 = 0; k0 < K; k0 += 32) {
    int kk = k0 + quad * 8;
    short8 a;
    if (AFP32) {
      const float4* ap = reinterpret_cast<const float4*>((const float*)Av + (size_t)m * K + kk);
      float4 lo = ap[0], hi = ap[1];
      union { short8 v; unsigned short u[8]; } pa;
      pa.u[0]=f2bf(lo.x); pa.u[1]=f2bf(lo.y); pa.u[2]=f2bf(lo.z); pa.u[3]=f2bf(lo.w);
      pa.u[4]=f2bf(hi.x); pa.u[5]=f2bf(hi.y); pa.u[6]=f2bf(hi.z); pa.u[7]=f2bf(hi.w);
      a = pa.v;
    } else {
      a = *reinterpret_cast<const short8*>((const unsigned short*)Av + (size_t)m * K + kk);
    }
    #pragma unroll
    for (int t = 0; t < 8; ++t) {
      short8 b = *reinterpret_cast<const short8*>(Bt + (size_t)(t*16 + r) * K + kk);
      acc[t] = __builtin_amdgcn_mfma_f32_16x16x32_bf16(a, b, acc[t], 0, 0, 0);
    }
  }
  float asv[8], adv[8];
  #pragma unroll
  for (int t = 0; t < 8; ++t) {
    int col = t * 16 + r;
    asv[t] = a_src[col]; adv[t] = a_dst[col];
  }
  #pragma unroll
  for (int rr = 0; rr < 4; ++rr) {
    float ps = 0.f, pd = 0.f;
    #pragma unroll
    for (int t = 0; t < 8; ++t) { ps += acc[t][rr] * asv[t]; pd += acc[t][rr] * adv[t]; }
    #pragma unroll
    for (int mo = 1; mo <= 8; mo <<= 1) { ps += __shfl_xor(ps, mo); pd += __shfl_xor(pd, mo); }
    if (r == 0) {
      int row = mt * 16 + quad * 4 + rr;
      alps[row] = ps;
      alpd[row] = pd;
    }
  }
  #pragma unroll
  for (int t = 0; t < 8; ++t) {
    int col = t * 16 + r;
    #pragma unroll
    for (int rr = 0; rr < 4; ++rr) {
      int row = mt * 16 + quad * 4 + rr;
      C[(size_t)row * 128 + col] = f2bf(acc[t][rr]);
    }
  }
}

template <int K, bool AFP32>
__global__ __launch_bounds__(256) void k_gemm(const void* __restrict__ Av, const unsigned short* __restrict__ Bt,
                                              unsigned short* __restrict__ C,
                                              const float* __restrict__ a_src, const float* __restrict__ a_dst,
                                              float* __restrict__ alps, float* __restrict__ alpd, int M) {
  int wid = (blockIdx.x * 256 + threadIdx.x) >> 6;
  int lane = threadIdx.x & 63;
  gemm_body<K, AFP32>(wid, lane, Av, Bt, C, a_src, a_dst, alps, alpd, M);
}

// ---------------- fused GEMM1 + dual scatter (csr + src-sorted edge recs) ----------------
__global__ __launch_bounds__(256) void k_scatgemm(
                       const int* __restrict__ src, const int* __restrict__ dst,
                       const int* __restrict__ eslot, const int* __restrict__ rowptr,
                       const int* __restrict__ sslot, const int* __restrict__ srowptr,
                       const float2* __restrict__ edgeD, float4* __restrict__ csr,
                       uint2* __restrict__ sedge,
                       int E, int half, int GB,
                       const float* __restrict__ x, const unsigned short* __restrict__ W1t,
                       unsigned short* __restrict__ hA,
                       const float* __restrict__ a_src, const float* __restrict__ a_dst,
                       float* __restrict__ alps, float* __restrict__ alpd, int N) {
  int t = threadIdx.x;
  if (blockIdx.x < (unsigned)GB) {
    int wid = (blockIdx.x * 256 + t) >> 6;
    int lane = t & 63;
    gemm_body<256, true>(wid, lane, x, W1t, hA, a_src, a_dst, alps, alpd, N);
    return;
  }
  int e = (blockIdx.x - GB) * 256 + t;
  if (e >= E) return;
  int s = src[e], d = dst[e];
  float2 dd = edgeD[e];
  int slot = rowptr[d] + eslot[e];
  float4 v;
  v.x = __int_as_float(s); v.y = dd.x; v.z = dd.y; v.w = 0.f;
  csr[slot] = v;
  int ss = srowptr[s] + sslot[e];
  int outidx = (e < half) ? e : e - half;
  uint2 rec;
  rec.x = (unsigned)s | ((unsigned)d << 16);       // N < 65536 for both fields
  rec.y = (unsigned)outidx;
  sedge[ss] = rec;
}

// online-softmax aggregation; wave per node, 4 edge streams (quarter-wave each),
// lane owns 8 channels (uint4 = 8 bf16); 3-deep csr pipeline + 2-deep (as_,h) gathers.
// Defer-max: rescale only when new alpha exceeds running max by >8 (e^8 headroom).
__global__ __launch_bounds__(256) void k_agg(const int* __restrict__ rowptr, const float4* __restrict__ csr,
                      const float* __restrict__ as_, const float* __restrict__ ad_,
                      const unsigned short* __restrict__ h, const float* __restrict__ bias,
                      unsigned short* __restrict__ out, int N, int use2, int do_relu) {
  int i = (blockIdx.x * blockDim.x + threadIdx.x) >> 6;
  int lane = threadIdx.x & 63;
  if (i >= N) return;
  int st = lane >> 4;       // stream 0..3
  int q  = lane & 15;       // channel group: ch [8q, 8q+8)
  int start = rowptr[i], end = rowptr[i + 1];
  int cnt = end - start;
  float adi = ad_[i], asi = as_[i];
  float m = -3.0e38f, s = 0.f, esum = 0.f;
  float acc[8] = {};
  int idx = start + st;
  float4 cur, nx1, nx2;
  float as_c = 0.f, as_1 = 0.f;
  uint4 hv_c, hv_1;
  if (idx < end) cur = csr[idx];
  if (idx + 4 < end) nx1 = csr[idx + 4];
  if (idx + 8 < end) nx2 = csr[idx + 8];
  if (idx < end) {
    int sv = __float_as_int(cur.x);
    as_c = as_[sv];
    hv_c = *reinterpret_cast<const uint4*>(h + (size_t)sv * 128 + q * 8);
  }
  if (idx + 4 < end) {
    int sv = __float_as_int(nx1.x);
    as_1 = as_[sv];
    hv_1 = *reinterpret_cast<const uint4*>(h + (size_t)sv * 128 + q * 8);
  }
  for (; idx < end; idx += 4) {
    float4 n3;
    if (idx + 12 < end) n3 = csr[idx + 12];
    float as_2 = 0.f; uint4 hv_2;
    if (idx + 8 < end) {
      int sv = __float_as_int(nx2.x);
      as_2 = as_[sv];
      hv_2 = *reinterpret_cast<const uint4*>(h + (size_t)sv * 128 + q * 8);
    }
    float e = use2 ? cur.z : cur.y;
    float a = lrelu(as_c + adi + e);
    esum += e;
    if (a > m + 8.f) {
      float rr = __expf(m - a);
      s *= rr;
      #pragma unroll
      for (int j = 0; j < 8; ++j) acc[j] *= rr;
      m = a;
    }
    float w = __expf(a - m);
    s += w;
    acc[0] += w * bflo(hv_c.x); acc[1] += w * bfhi(hv_c.x);
    acc[2] += w * bflo(hv_c.y); acc[3] += w * bfhi(hv_c.y);
    acc[4] += w * bflo(hv_c.z); acc[5] += w * bfhi(hv_c.z);
    acc[6] += w * bflo(hv_c.w); acc[7] += w * bfhi(hv_c.w);
    cur = nx1; nx1 = nx2; nx2 = n3;
    as_c = as_1; hv_c = hv_1;
    as_1 = as_2; hv_1 = hv_2;
  }
  // merge 4 streams: xor 16 then xor 32
  #pragma unroll
  for (int off = 16; off <= 32; off <<= 1) {
    float m_o = __shfl_xor(m, off);
    float s_o = __shfl_xor(s, off);
    float e_o = __shfl_xor(esum, off);
    float ao[8];
    #pragma unroll
    for (int j = 0; j < 8; ++j) ao[j] = __shfl_xor(acc[j], off);
    float Mn = fmaxf(m, m_o);
    float f  = __expf(m - Mn), fo = __expf(m_o - Mn);
    s = s * f + s_o * fo;
    #pragma unroll
    for (int j = 0; j < 8; ++j) acc[j] = acc[j] * f + ao[j] * fo;
    esum += e_o;
    m = Mn;
  }
  // merge self-loop
  float a_self = lrelu(asi + adi + esum / fmaxf((float)cnt, 1.f));
  float M2 = fmaxf(m, a_self);
  float g = __expf(m - M2);
  float w_self = __expf(a_self - M2);
  s = s * g + w_self;
  uint4 hs = *reinterpret_cast<const uint4*>(h + (size_t)i * 128 + q * 8);
  float hsf[8] = { bflo(hs.x), bfhi(hs.x), bflo(hs.y), bfhi(hs.y),
                   bflo(hs.z), bfhi(hs.z), bflo(hs.w), bfhi(hs.w) };
  #pragma unroll
  for (int j = 0; j < 8; ++j) acc[j] = acc[j] * g + w_self * hsf[j];
  float inv = 1.0f / s;
  float4 bv0 = *reinterpret_cast<const float4*>(bias + q * 8);
  float4 bv1 = *reinterpret_cast<const float4*>(bias + q * 8 + 4);
  float o[8];
  o[0] = acc[0]*inv + bv0.x; o[1] = acc[1]*inv + bv0.y;
  o[2] = acc[2]*inv + bv0.z; o[3] = acc[3]*inv + bv0.w;
  o[4] = acc[4]*inv + bv1.x; o[5] = acc[5]*inv + bv1.y;
  o[6] = acc[6]*inv + bv1.z; o[7] = acc[7]*inv + bv1.w;
  if (do_relu) {
    #pragma unroll
    for (int j = 0; j < 8; ++j) o[j] = fmaxf(o[j], 0.f);
  }
  if (st == 0) {
    uint4 ov;
    ov.x = (unsigned)f2bf(o[0]) | ((unsigned)f2bf(o[1]) << 16);
    ov.y = (unsigned)f2bf(o[2]) | ((unsigned)f2bf(o[3]) << 16);
    ov.z = (unsigned)f2bf(o[4]) | ((unsigned)f2bf(o[5]) << 16);
    ov.w = (unsigned)f2bf(o[6]) | ((unsigned)f2bf(o[7]) << 16);
    *reinterpret_cast<uint4*>(out + (size_t)i * 128 + q * 8) = ov;
  }
}

// src-sorted decode: 8-lane group per sorted edge record; z[src] rows are shared
// by consecutive records (L1/L2 hits); z[dst] random; fp32 atomicAdd into zeroed out.
__global__ __launch_bounds__(256) void k_decode_sorted(const uint2* __restrict__ sedge,
                         const unsigned short* __restrict__ z, float* __restrict__ out, int E) {
  int j = (blockIdx.x * 256 + threadIdx.x) >> 3;    // record index
  if (j >= E) return;
  int q = threadIdx.x & 7;                          // channel group: shorts [16q,16q+16)
  uint2 rec = sedge[j];
  int s = rec.x & 0xffff;
  int d = rec.x >> 16;
  const uint4* za = reinterpret_cast<const uint4*>(z + (size_t)s * 128 + q * 16);
  const uint4* zb = reinterpret_cast<const uint4*>(z + (size_t)d * 128 + q * 16);
  uint4 a0 = za[0], a1 = za[1];
  uint4 b0 = zb[0], b1 = zb[1];
  float p = bflo(a0.x)*bflo(b0.x) + bfhi(a0.x)*bfhi(b0.x)
          + bflo(a0.y)*bflo(b0.y) + bfhi(a0.y)*bfhi(b0.y)
          + bflo(a0.z)*bflo(b0.z) + bfhi(a0.z)*bfhi(b0.z)
          + bflo(a0.w)*bflo(b0.w) + bfhi(a0.w)*bfhi(b0.w)
          + bflo(a1.x)*bflo(b1.x) + bfhi(a1.x)*bfhi(b1.x)
          + bflo(a1.y)*bflo(b1.y) + bfhi(a1.y)*bfhi(b1.y)
          + bflo(a1.z)*bflo(b1.z) + bfhi(a1.z)*bfhi(b1.z)
          + bflo(a1.w)*bflo(b1.w) + bfhi(a1.w)*bfhi(b1.w);
  p += __shfl_xor(p, 1);
  p += __shfl_xor(p, 2);
  p += __shfl_xor(p, 4);
  if (q == 0) atomicAdd(out + rec.y, p);
}

extern "C" void kernel_launch(void* const* d_in, const int* in_sizes, int n_in,
                              void* d_out, int out_size, void* d_ws, size_t ws_size,
                              hipStream_t stream) {
  const int H = 128;
  const int N = in_sizes[0] / 256;        // 50000
  const int E = in_sizes[1] / 2;          // 800000
  const int half = E / 2;

  const float* x   = (const float*)d_in[0];
  const int* eidx  = (const int*)d_in[1];
  const float* ef  = (const float*)d_in[2];
  const float* W1  = (const float*)d_in[4];
  const float* as1 = (const float*)d_in[5];
  const float* ad1 = (const float*)d_in[6];
  const float* We1 = (const float*)d_in[7];
  const float* ae1 = (const float*)d_in[8];
  const float* b1  = (const float*)d_in[9];
  const float* W2  = (const float*)d_in[10];
  const float* as2 = (const float*)d_in[11];
  const float* ad2 = (const float*)d_in[12];
  const float* We2 = (const float*)d_in[13];
  const float* ae2 = (const float*)d_in[14];
  const float* b2  = (const float*)d_in[15];

  const int* src = eidx;
  const int* dst = eidx + E;

  size_t off = 0;
  auto alloc = [&](size_t bytes) -> void* {
    void* p = (char*)d_ws + off;
    off += (bytes + 255) & ~(size_t)255;
    return p;
  };
  float*  we1    = (float*)alloc(64 * 4);
  float*  we2    = (float*)alloc(64 * 4);
  int*    degs   = (int*)alloc((size_t)N * 4 * 2);   // degi | sdeg, one memset
  int*    degi   = degs;
  int*    sdeg   = degs + N;
  float*  alps   = (float*)alloc((size_t)N * 4);
  float*  alpd   = (float*)alloc((size_t)N * 4);
  int*    eslot  = (int*)alloc((size_t)E * 4);
  int*    sslot  = (int*)alloc((size_t)E * 4);
  int*    rowptr = (int*)alloc((size_t)(N + 1) * 4);
  int*    srowptr= (int*)alloc((size_t)(N + 1) * 4);
  float2* edgeD  = (float2*)alloc((size_t)E * 8);
  float4* csr    = (float4*)alloc((size_t)E * 16);
  uint2*  sedge  = (uint2*)alloc((size_t)E * 8);
  unsigned short* W1t = (unsigned short*)alloc((size_t)128 * 256 * 2);
  unsigned short* W2t = (unsigned short*)alloc((size_t)128 * 128 * 2);
  unsigned short* hA  = (unsigned short*)alloc((size_t)N * H * 2);
  unsigned short* hB  = (unsigned short*)alloc((size_t)N * H * 2);

  hipMemsetAsync(degs, 0, (size_t)N * 8, stream);
  hipMemsetAsync(d_out, 0, (size_t)out_size, stream);

  int CB = (E + 255) / 256;                         // count blocks
  k_prep<<<CB + 193, 256, 0, stream>>>(src, dst, degi, sdeg, eslot, sslot, E, CB,
                                       We1, ae1, We2, ae2, we1, we2, W1, W1t, W2, W2t);

  // ---- dual scan (2 blocks) overlapped with streaming e-dot ----
  int EDOTB = 782;
  k_scanedot<<<2 + EDOTB, 1024, 0, stream>>>(degi, rowptr, sdeg, srowptr, N, E,
                                             ef, we1, we2, edgeD, EDOTB);

  int gwaves = (N + 15) / 16;                       // full-width waves
  int GB = (gwaves + 3) / 4;
  int SB = (E + 255) / 256;
  // ---- layer 1 GEMM (+alpha) overlapped with dual scatter ----
  k_scatgemm<<<GB + SB, 256, 0, stream>>>(src, dst, eslot, rowptr, sslot, srowptr,
                                          edgeD, csr, sedge, E, half, GB,
                                          x, W1t, hA, as1, ad1, alps, alpd, N);
  k_agg<<<(N + 3) / 4, 256, 0, stream>>>(rowptr, csr, alps, alpd, hA, b1, hB, N, 0, 1);
  // ---- layer 2 ----
  k_gemm<128, false><<<GB, 256, 0, stream>>>(hB, W2t, hA, as2, ad2, alps, alpd, N);
  k_agg<<<(N + 3) / 4, 256, 0, stream>>>(rowptr, csr, alps, alpd, hA, b2, hB, N, 1, 0);
  // ---- decode (src-sorted, atomic accumulate) ----
  int DB = (E * 8 + 255) / 256;
  k_decode_sorted<<<DB, 256, 0, stream>>>(sedge, hB, (float*)d_out, E);
}

// Round 7
// 579.520 us; speedup vs baseline: 1.0447x; 1.0447x over previous
//
#include <hip/hip_runtime.h>
#include <hip/hip_bf16.h>

typedef __attribute__((ext_vector_type(8))) short short8;
typedef __attribute__((ext_vector_type(4))) float floatx4;

__device__ __forceinline__ float lrelu(float a){ return a > 0.f ? a : 0.2f * a; }
__device__ __forceinline__ float bflo(unsigned u){ return __uint_as_float(u << 16); }
__device__ __forceinline__ float bfhi(unsigned u){ return __uint_as_float(u & 0xffff0000u); }
__device__ __forceinline__ unsigned short f2bf(float f){
  __hip_bfloat16 h = __float2bfloat16(f);
  return *reinterpret_cast<unsigned short*>(&h);
}
__device__ __forceinline__ float dot4(float4 a, float4 b){
  return a.x*b.x + a.y*b.y + a.z*b.z + a.w*b.w;
}

// ---------------- fused prep + count ----------------
// blocks [0, CB): per-edge slot within dst bucket (atomics into degi)
// block CB+0 -> we1/we2 dots ; CB+1..CB+128 -> W1t ; CB+129..CB+192 -> W2t
__global__ __launch_bounds__(256) void k_prep(const int* __restrict__ dst, int* __restrict__ degi,
                       int* __restrict__ eslot, int E, int CB,
                       const float* __restrict__ We1, const float* __restrict__ ae1,
                       const float* __restrict__ We2, const float* __restrict__ ae2,
                       float* __restrict__ we1, float* __restrict__ we2,
                       const float* __restrict__ W1, unsigned short* __restrict__ W1t,
                       const float* __restrict__ W2, unsigned short* __restrict__ W2t) {
  int t = threadIdx.x;
  if (blockIdx.x < (unsigned)CB) {
    int e = blockIdx.x * 256 + t;
    if (e < E) eslot[e] = atomicAdd(degi + dst[e], 1);
    return;
  }
  int b = blockIdx.x - CB;
  if (b == 0) {
    if (t >= 64) return;
    float s1 = 0.f, s2 = 0.f;
    if (t < 60) {
      const float4* r1 = reinterpret_cast<const float4*>(We1 + t * 128);
      const float4* r2 = reinterpret_cast<const float4*>(We2 + t * 128);
      const float4* a1 = reinterpret_cast<const float4*>(ae1);
      const float4* a2 = reinterpret_cast<const float4*>(ae2);
      for (int i = 0; i < 32; ++i) {
        float4 x1 = r1[i], y1 = a1[i];
        float4 x2 = r2[i], y2 = a2[i];
        s1 += x1.x*y1.x + x1.y*y1.y + x1.z*y1.z + x1.w*y1.w;
        s2 += x2.x*y2.x + x2.y*y2.y + x2.z*y2.z + x2.w*y2.w;
      }
    }
    we1[t] = s1; we2[t] = s2;
  } else if (b <= 128) {
    int idx = (b - 1) * 256 + t;            // K=256: 32768 elems
    int k = idx >> 7, n = idx & 127;
    W1t[(size_t)n * 256 + k] = f2bf(W1[idx]);
  } else {
    int idx = (b - 129) * 256 + t;          // K=128: 16384 elems
    int k = idx >> 7, n = idx & 127;
    W2t[(size_t)n * 128 + k] = f2bf(W2[idx]);
  }
}

// single-block exclusive scan body (1024 threads); wave shfl_up scans, 2 barriers
__device__ __forceinline__ void scan_body(const int* __restrict__ degi, int* __restrict__ rowptr,
                                          int N, int E) {
  __shared__ int wsums[16];
  int t = threadIdx.x;
  int wave = t >> 6, lane = t & 63;
  const int CH = 52;                 // 13 * int4 ; 1024*52 = 53248 >= N
  int lo = t * CH;
  int v[52];
  int s = 0;
  #pragma unroll
  for (int i = 0; i < 13; ++i) {
    int base_i = lo + 4 * i;
    if (base_i + 4 <= N) {
      int4 q = *reinterpret_cast<const int4*>(degi + base_i);
      v[4*i+0] = q.x; v[4*i+1] = q.y; v[4*i+2] = q.z; v[4*i+3] = q.w;
      s += q.x + q.y + q.z + q.w;
    } else {
      #pragma unroll
      for (int j = 0; j < 4; ++j) {
        int idx = base_i + j;
        int x = (idx < N) ? degi[idx] : 0;
        v[4*i+j] = x; s += x;
      }
    }
  }
  int inc = s;
  #pragma unroll
  for (int off = 1; off < 64; off <<= 1) {
    int u = __shfl_up(inc, off);
    if (lane >= off) inc += u;
  }
  if (lane == 63) wsums[wave] = inc;
  __syncthreads();
  if (wave == 0) {
    int ws = (lane < 16) ? wsums[lane] : 0;
    #pragma unroll
    for (int off = 1; off < 16; off <<= 1) {
      int u = __shfl_up(ws, off);
      if (lane >= off) ws += u;
    }
    if (lane < 16) wsums[lane] = ws;
  }
  __syncthreads();
  int base = inc - s + (wave ? wsums[wave - 1] : 0);
  #pragma unroll
  for (int i = 0; i < 13; ++i) {
    int base_i = lo + 4 * i;
    if (base_i + 4 <= N) {
      int4 o;
      o.x = base; base += v[4*i+0];
      o.y = base; base += v[4*i+1];
      o.z = base; base += v[4*i+2];
      o.w = base; base += v[4*i+3];
      *reinterpret_cast<int4*>(rowptr + base_i) = o;
    } else {
      #pragma unroll
      for (int j = 0; j < 4; ++j) {
        int idx = base_i + j;
        if (idx < N) { rowptr[idx] = base; base += v[4*i+j]; }
      }
    }
  }
  if (t == 0) rowptr[N] = E;
}

// ---------------- fused scan + streaming e-dot ----------------
__global__ __launch_bounds__(1024) void k_scanedot(const int* __restrict__ degi, int* __restrict__ rowptr,
                       int N, int E,
                       const float* __restrict__ ef,
                       const float* __restrict__ we1, const float* __restrict__ we2,
                       float2* __restrict__ edgeD, int EDOTB) {
  if (blockIdx.x == 0) { scan_body(degi, rowptr, N, E); return; }
  int t = threadIdx.x;
  int sub = t & 3;
  int qw = (int)(blockIdx.x - 1) * 256 + (t >> 2);
  const float4* w1v = reinterpret_cast<const float4*>(we1);
  const float4* w2v = reinterpret_cast<const float4*>(we2);
  float4 wa0 = w1v[sub],     wb0 = w2v[sub];
  float4 wa1 = w1v[sub + 4], wb1 = w2v[sub + 4];
  float4 wa2 = w1v[sub + 8], wb2 = w2v[sub + 8];
  bool has3 = sub < 3;
  float4 wa3 = make_float4(0.f,0.f,0.f,0.f), wb3 = wa3;
  if (has3) { wa3 = w1v[sub + 12]; wb3 = w2v[sub + 12]; }
  const float4* efq = reinterpret_cast<const float4*>(ef);
  int stride = EDOTB * 256;
  for (int e = qw; e < E; e += stride) {
    size_t b = (size_t)e * 15;
    float4 f0 = efq[b + sub];
    float4 f1 = efq[b + sub + 4];
    float4 f2 = efq[b + sub + 8];
    float4 f3 = make_float4(0.f,0.f,0.f,0.f);
    if (has3) f3 = efq[b + sub + 12];
    float d1 = dot4(f0, wa0) + dot4(f1, wa1) + dot4(f2, wa2) + dot4(f3, wa3);
    float d2 = dot4(f0, wb0) + dot4(f1, wb1) + dot4(f2, wb2) + dot4(f3, wb3);
    d1 += __shfl_xor(d1, 1); d1 += __shfl_xor(d1, 2);
    d2 += __shfl_xor(d2, 1); d2 += __shfl_xor(d2, 2);
    if (sub == 0) edgeD[e] = make_float2(d1, d2);
  }
}

// Full-width MFMA GEMM body: one wave computes C[16,128] = A[16,K] @ Bt[128,K]^T.
template <int K, bool AFP32>
__device__ __forceinline__ void gemm_body(int wid, int lane,
    const void* __restrict__ Av, const unsigned short* __restrict__ Bt,
    unsigned short* __restrict__ C,
    const float* __restrict__ a_src, const float* __restrict__ a_dst,
    float* __restrict__ alps, float* __restrict__ alpd, int M) {
  int mt = wid;
  if (mt * 16 >= M) return;
  int r = lane & 15, quad = lane >> 4;
  int m = mt * 16 + r;
  floatx4 acc[8] = {};
  for (int k0 = 0; k0 < K; k0 += 32) {
    int kk = k0 + quad * 8;
    short8 a;
    if (AFP32) {
      const float4* ap = reinterpret_cast<const float4*>((const float*)Av + (size_t)m * K + kk);
      float4 lo = ap[0], hi = ap[1];
      union { short8 v; unsigned short u[8]; } pa;
      pa.u[0]=f2bf(lo.x); pa.u[1]=f2bf(lo.y); pa.u[2]=f2bf(lo.z); pa.u[3]=f2bf(lo.w);
      pa.u[4]=f2bf(hi.x); pa.u[5]=f2bf(hi.y); pa.u[6]=f2bf(hi.z); pa.u[7]=f2bf(hi.w);
      a = pa.v;
    } else {
      a = *reinterpret_cast<const short8*>((const unsigned short*)Av + (size_t)m * K + kk);
    }
    #pragma unroll
    for (int t = 0; t < 8; ++t) {
      short8 b = *reinterpret_cast<const short8*>(Bt + (size_t)(t*16 + r) * K + kk);
      acc[t] = __builtin_amdgcn_mfma_f32_16x16x32_bf16(a, b, acc[t], 0, 0, 0);
    }
  }
  float asv[8], adv[8];
  #pragma unroll
  for (int t = 0; t < 8; ++t) {
    int col = t * 16 + r;
    asv[t] = a_src[col]; adv[t] = a_dst[col];
  }
  #pragma unroll
  for (int rr = 0; rr < 4; ++rr) {
    float ps = 0.f, pd = 0.f;
    #pragma unroll
    for (int t = 0; t < 8; ++t) { ps += acc[t][rr] * asv[t]; pd += acc[t][rr] * adv[t]; }
    #pragma unroll
    for (int mo = 1; mo <= 8; mo <<= 1) { ps += __shfl_xor(ps, mo); pd += __shfl_xor(pd, mo); }
    if (r == 0) {
      int row = mt * 16 + quad * 4 + rr;
      alps[row] = ps;
      alpd[row] = pd;
    }
  }
  #pragma unroll
  for (int t = 0; t < 8; ++t) {
    int col = t * 16 + r;
    #pragma unroll
    for (int rr = 0; rr < 4; ++rr) {
      int row = mt * 16 + quad * 4 + rr;
      C[(size_t)row * 128 + col] = f2bf(acc[t][rr]);
    }
  }
}

template <int K, bool AFP32>
__global__ __launch_bounds__(256) void k_gemm(const void* __restrict__ Av, const unsigned short* __restrict__ Bt,
                                              unsigned short* __restrict__ C,
                                              const float* __restrict__ a_src, const float* __restrict__ a_dst,
                                              float* __restrict__ alps, float* __restrict__ alpd, int M) {
  int wid = (blockIdx.x * 256 + threadIdx.x) >> 6;
  int lane = threadIdx.x & 63;
  gemm_body<K, AFP32>(wid, lane, Av, Bt, C, a_src, a_dst, alps, alpd, M);
}

// ---------------- fused GEMM1 + CSR scatter ----------------
__global__ __launch_bounds__(256) void k_scatgemm(
                       const int* __restrict__ src, const int* __restrict__ dst,
                       const int* __restrict__ eslot, const int* __restrict__ rowptr,
                       const float2* __restrict__ edgeD, float4* __restrict__ csr,
                       int E, int GB,
                       const float* __restrict__ x, const unsigned short* __restrict__ W1t,
                       unsigned short* __restrict__ hA,
                       const float* __restrict__ a_src, const float* __restrict__ a_dst,
                       float* __restrict__ alps, float* __restrict__ alpd, int N) {
  int t = threadIdx.x;
  if (blockIdx.x < (unsigned)GB) {
    int wid = (blockIdx.x * 256 + t) >> 6;
    int lane = t & 63;
    gemm_body<256, true>(wid, lane, x, W1t, hA, a_src, a_dst, alps, alpd, N);
    return;
  }
  int e = (blockIdx.x - GB) * 256 + t;
  if (e >= E) return;
  int d = dst[e];
  float2 dd = edgeD[e];
  int slot = rowptr[d] + eslot[e];
  float4 v;
  v.x = __int_as_float(src[e]); v.y = dd.x; v.z = dd.y; v.w = 0.f;
  csr[slot] = v;
}

// online-softmax aggregation; TWO waves per node (8 edge streams), block = 2 nodes.
// lane owns 8 channels (uint4 = 8 bf16); 2-deep csr prefetch + 1-deep gather pipeline.
// Cross-wave merge via LDS. Defer-max rescale (>8 threshold, e^8 headroom).
__global__ __launch_bounds__(256) void k_agg(const int* __restrict__ rowptr, const float4* __restrict__ csr,
                      const float* __restrict__ as_, const float* __restrict__ ad_,
                      const unsigned short* __restrict__ h, const float* __restrict__ bias,
                      unsigned short* __restrict__ out, int N, int use2, int do_relu) {
  __shared__ float mrg[2][16][11];
  int tid = threadIdx.x;
  int nb = tid >> 7;                  // node within block (0..1)
  int i = blockIdx.x * 2 + nb;
  int wv = (tid >> 6) & 1;            // wave within node
  int lane = tid & 63;
  int st = wv * 4 + (lane >> 4);      // stream 0..7
  int q  = lane & 15;                 // channel group: ch [8q, 8q+8)
  bool valid = i < N;
  int start = 0, end = 0;
  float adi = 0.f, asi = 0.f;
  if (valid) { start = rowptr[i]; end = rowptr[i + 1]; adi = ad_[i]; asi = as_[i]; }
  int cnt = end - start;
  float m = -3.0e38f, s = 0.f, esum = 0.f;
  float acc[8] = {};
  int idx = start + st;
  float4 cur, nx;
  float as_c = 0.f; uint4 hv_c;
  if (idx < end) {
    cur = csr[idx];
    int sv = __float_as_int(cur.x);
    as_c = as_[sv];
    hv_c = *reinterpret_cast<const uint4*>(h + (size_t)sv * 128 + q * 8);
  }
  if (idx + 8 < end) nx = csr[idx + 8];
  for (; idx < end; idx += 8) {
    float4 n2;
    if (idx + 16 < end) n2 = csr[idx + 16];
    float as_n = 0.f; uint4 hv_n;
    if (idx + 8 < end) {
      int svn = __float_as_int(nx.x);
      as_n = as_[svn];
      hv_n = *reinterpret_cast<const uint4*>(h + (size_t)svn * 128 + q * 8);
    }
    float e = use2 ? cur.z : cur.y;
    float a = lrelu(as_c + adi + e);
    esum += e;
    if (a > m + 8.f) {
      float rr = __expf(m - a);
      s *= rr;
      #pragma unroll
      for (int j = 0; j < 8; ++j) acc[j] *= rr;
      m = a;
    }
    float w = __expf(a - m);
    s += w;
    acc[0] += w * bflo(hv_c.x); acc[1] += w * bfhi(hv_c.x);
    acc[2] += w * bflo(hv_c.y); acc[3] += w * bfhi(hv_c.y);
    acc[4] += w * bflo(hv_c.z); acc[5] += w * bfhi(hv_c.z);
    acc[6] += w * bflo(hv_c.w); acc[7] += w * bfhi(hv_c.w);
    cur = nx; nx = n2; as_c = as_n; hv_c = hv_n;
  }
  // intra-wave merge of 4 streams: xor 16 then xor 32
  #pragma unroll
  for (int off = 16; off <= 32; off <<= 1) {
    float m_o = __shfl_xor(m, off);
    float s_o = __shfl_xor(s, off);
    float e_o = __shfl_xor(esum, off);
    float ao[8];
    #pragma unroll
    for (int j = 0; j < 8; ++j) ao[j] = __shfl_xor(acc[j], off);
    float Mn = fmaxf(m, m_o);
    float f  = __expf(m - Mn), fo = __expf(m_o - Mn);
    s = s * f + s_o * fo;
    #pragma unroll
    for (int j = 0; j < 8; ++j) acc[j] = acc[j] * f + ao[j] * fo;
    esum += e_o;
    m = Mn;
  }
  // cross-wave merge via LDS (wave1 publishes, wave0 merges)
  if (wv == 1 && lane < 16) {
    mrg[nb][q][0] = m; mrg[nb][q][1] = s; mrg[nb][q][2] = esum;
    #pragma unroll
    for (int j = 0; j < 8; ++j) mrg[nb][q][3 + j] = acc[j];
  }
  __syncthreads();
  if (wv != 0 || !valid) return;
  {
    float m_o = mrg[nb][q][0];
    float s_o = mrg[nb][q][1];
    float e_o = mrg[nb][q][2];
    float Mn = fmaxf(m, m_o);
    float f  = __expf(m - Mn), fo = __expf(m_o - Mn);
    s = s * f + s_o * fo;
    #pragma unroll
    for (int j = 0; j < 8; ++j) acc[j] = acc[j] * f + mrg[nb][q][3 + j] * fo;
    esum += e_o;
    m = Mn;
  }
  // merge self-loop
  float a_self = lrelu(asi + adi + esum / fmaxf((float)cnt, 1.f));
  float M2 = fmaxf(m, a_self);
  float g = __expf(m - M2);
  float w_self = __expf(a_self - M2);
  s = s * g + w_self;
  uint4 hs = *reinterpret_cast<const uint4*>(h + (size_t)i * 128 + q * 8);
  float hsf[8] = { bflo(hs.x), bfhi(hs.x), bflo(hs.y), bfhi(hs.y),
                   bflo(hs.z), bfhi(hs.z), bflo(hs.w), bfhi(hs.w) };
  #pragma unroll
  for (int j = 0; j < 8; ++j) acc[j] = acc[j] * g + w_self * hsf[j];
  float inv = 1.0f / s;
  float4 bv0 = *reinterpret_cast<const float4*>(bias + q * 8);
  float4 bv1 = *reinterpret_cast<const float4*>(bias + q * 8 + 4);
  float o[8];
  o[0] = acc[0]*inv + bv0.x; o[1] = acc[1]*inv + bv0.y;
  o[2] = acc[2]*inv + bv0.z; o[3] = acc[3]*inv + bv0.w;
  o[4] = acc[4]*inv + bv1.x; o[5] = acc[5]*inv + bv1.y;
  o[6] = acc[6]*inv + bv1.z; o[7] = acc[7]*inv + bv1.w;
  if (do_relu) {
    #pragma unroll
    for (int j = 0; j < 8; ++j) o[j] = fmaxf(o[j], 0.f);
  }
  if (lane < 16) {
    uint4 ov;
    ov.x = (unsigned)f2bf(o[0]) | ((unsigned)f2bf(o[1]) << 16);
    ov.y = (unsigned)f2bf(o[2]) | ((unsigned)f2bf(o[3]) << 16);
    ov.z = (unsigned)f2bf(o[4]) | ((unsigned)f2bf(o[5]) << 16);
    ov.w = (unsigned)f2bf(o[6]) | ((unsigned)f2bf(o[7]) << 16);
    *reinterpret_cast<uint4*>(out + (size_t)i * 128 + q * 8) = ov;
  }
}

// decode: wave handles 4 k's; 8-lane group per (k, half); lane owns 16 channels (2x uint4)
__global__ void k_decode(const int* __restrict__ src, const int* __restrict__ dst,
                         const unsigned short* __restrict__ z, float* __restrict__ out, int halfE) {
  int w = (blockIdx.x * blockDim.x + threadIdx.x) >> 6;
  int lane = threadIdx.x & 63;
  int k0 = w * 4;
  if (k0 >= halfE) return;
  int g = lane >> 3;           // 0..7 : r = g>>1 (k index), hh = g&1 (half)
  int q = lane & 7;            // channel group: shorts [16q, 16q+16)
  int r = g >> 1, hh = g & 1;
  int k = k0 + r;
  float p = 0.f;
  if (k < halfE) {
    int e = k + hh * halfE;
    int sv = src[e], dv = dst[e];
    const uint4* za = reinterpret_cast<const uint4*>(z + (size_t)sv * 128 + q * 16);
    const uint4* zb = reinterpret_cast<const uint4*>(z + (size_t)dv * 128 + q * 16);
    uint4 a0 = za[0], a1 = za[1];
    uint4 b0 = zb[0], b1 = zb[1];
    p = bflo(a0.x)*bflo(b0.x) + bfhi(a0.x)*bfhi(b0.x)
      + bflo(a0.y)*bflo(b0.y) + bfhi(a0.y)*bfhi(b0.y)
      + bflo(a0.z)*bflo(b0.z) + bfhi(a0.z)*bfhi(b0.z)
      + bflo(a0.w)*bflo(b0.w) + bfhi(a0.w)*bfhi(b0.w)
      + bflo(a1.x)*bflo(b1.x) + bfhi(a1.x)*bfhi(b1.x)
      + bflo(a1.y)*bflo(b1.y) + bfhi(a1.y)*bfhi(b1.y)
      + bflo(a1.z)*bflo(b1.z) + bfhi(a1.z)*bfhi(b1.z)
      + bflo(a1.w)*bflo(b1.w) + bfhi(a1.w)*bfhi(b1.w);
  }
  p += __shfl_xor(p, 1);
  p += __shfl_xor(p, 2);
  p += __shfl_xor(p, 4);       // sum over q within the 8-lane group
  p += __shfl_xor(p, 8);       // add the other half (hh)
  if ((lane & 15) == 0) {
    int kk = k0 + (lane >> 4);
    if (kk < halfE) out[kk] = p;   // 4 consecutive 4B stores -> one transaction
  }
}

extern "C" void kernel_launch(void* const* d_in, const int* in_sizes, int n_in,
                              void* d_out, int out_size, void* d_ws, size_t ws_size,
                              hipStream_t stream) {
  const int H = 128;
  const int N = in_sizes[0] / 256;        // 50000
  const int E = in_sizes[1] / 2;          // 800000
  const int half = E / 2;

  const float* x   = (const float*)d_in[0];
  const int* eidx  = (const int*)d_in[1];
  const float* ef  = (const float*)d_in[2];
  const float* W1  = (const float*)d_in[4];
  const float* as1 = (const float*)d_in[5];
  const float* ad1 = (const float*)d_in[6];
  const float* We1 = (const float*)d_in[7];
  const float* ae1 = (const float*)d_in[8];
  const float* b1  = (const float*)d_in[9];
  const float* W2  = (const float*)d_in[10];
  const float* as2 = (const float*)d_in[11];
  const float* ad2 = (const float*)d_in[12];
  const float* We2 = (const float*)d_in[13];
  const float* ae2 = (const float*)d_in[14];
  const float* b2  = (const float*)d_in[15];

  const int* src = eidx;
  const int* dst = eidx + E;

  size_t off = 0;
  auto alloc = [&](size_t bytes) -> void* {
    void* p = (char*)d_ws + off;
    off += (bytes + 255) & ~(size_t)255;
    return p;
  };
  float*  we1    = (float*)alloc(64 * 4);
  float*  we2    = (float*)alloc(64 * 4);
  int*    degi   = (int*)alloc((size_t)N * 4);
  float*  alps   = (float*)alloc((size_t)N * 4);
  float*  alpd   = (float*)alloc((size_t)N * 4);
  int*    eslot  = (int*)alloc((size_t)E * 4);
  int*    rowptr = (int*)alloc((size_t)(N + 1) * 4);
  float2* edgeD  = (float2*)alloc((size_t)E * 8);
  float4* csr    = (float4*)alloc((size_t)E * 16);
  unsigned short* W1t = (unsigned short*)alloc((size_t)128 * 256 * 2);
  unsigned short* W2t = (unsigned short*)alloc((size_t)128 * 128 * 2);
  unsigned short* hA  = (unsigned short*)alloc((size_t)N * H * 2);
  unsigned short* hB  = (unsigned short*)alloc((size_t)N * H * 2);

  hipMemsetAsync(degi, 0, (size_t)N * 4, stream);

  int CB = (E + 255) / 256;                         // count blocks
  k_prep<<<CB + 193, 256, 0, stream>>>(dst, degi, eslot, E, CB,
                                       We1, ae1, We2, ae2, we1, we2, W1, W1t, W2, W2t);

  // ---- scan (1 block) overlapped with streaming e-dot ----
  int EDOTB = 782;
  k_scanedot<<<1 + EDOTB, 1024, 0, stream>>>(degi, rowptr, N, E, ef, we1, we2, edgeD, EDOTB);

  int gwaves = (N + 15) / 16;                       // full-width waves
  int GB = (gwaves + 3) / 4;
  int SB = (E + 255) / 256;
  // ---- layer 1 GEMM (+alpha) overlapped with CSR scatter ----
  k_scatgemm<<<GB + SB, 256, 0, stream>>>(src, dst, eslot, rowptr, edgeD, csr, E, GB,
                                          x, W1t, hA, as1, ad1, alps, alpd, N);
  k_agg<<<(N + 1) / 2, 256, 0, stream>>>(rowptr, csr, alps, alpd, hA, b1, hB, N, 0, 1);
  // ---- layer 2 ----
  k_gemm<128, false><<<GB, 256, 0, stream>>>(hB, W2t, hA, as2, ad2, alps, alpd, N);
  k_agg<<<(N + 1) / 2, 256, 0, stream>>>(rowptr, csr, alps, alpd, hA, b2, hB, N, 1, 0);
  // ---- decode ----
  int dwaves = (half + 3) / 4;
  k_decode<<<(dwaves + 3) / 4, 256, 0, stream>>>(src, dst, hB, (float*)d_out, half);
}

// Round 8
// 563.221 us; speedup vs baseline: 1.0749x; 1.0289x over previous
//
#include <hip/hip_runtime.h>
#include <hip/hip_bf16.h>

typedef __attribute__((ext_vector_type(8))) short short8;
typedef __attribute__((ext_vector_type(4))) float floatx4;

__device__ __forceinline__ float lrelu(float a){ return a > 0.f ? a : 0.2f * a; }
__device__ __forceinline__ float bflo(unsigned u){ return __uint_as_float(u << 16); }
__device__ __forceinline__ float bfhi(unsigned u){ return __uint_as_float(u & 0xffff0000u); }
__device__ __forceinline__ unsigned short f2bf(float f){
  __hip_bfloat16 h = __float2bfloat16(f);
  return *reinterpret_cast<unsigned short*>(&h);
}
__device__ __forceinline__ float dot4(float4 a, float4 b){
  return a.x*b.x + a.y*b.y + a.z*b.z + a.w*b.w;
}

// ---------------- fused prep + count ----------------
// blocks [0, CB): per-edge slot within dst bucket (atomics into degi)
// block CB+0 -> we1/we2 dots ; CB+1..CB+128 -> W1t ; CB+129..CB+192 -> W2t
__global__ __launch_bounds__(256) void k_prep(const int* __restrict__ dst, int* __restrict__ degi,
                       int* __restrict__ eslot, int E, int CB,
                       const float* __restrict__ We1, const float* __restrict__ ae1,
                       const float* __restrict__ We2, const float* __restrict__ ae2,
                       float* __restrict__ we1, float* __restrict__ we2,
                       const float* __restrict__ W1, unsigned short* __restrict__ W1t,
                       const float* __restrict__ W2, unsigned short* __restrict__ W2t) {
  int t = threadIdx.x;
  if (blockIdx.x < (unsigned)CB) {
    int e = blockIdx.x * 256 + t;
    if (e < E) eslot[e] = atomicAdd(degi + dst[e], 1);
    return;
  }
  int b = blockIdx.x - CB;
  if (b == 0) {
    if (t >= 64) return;
    float s1 = 0.f, s2 = 0.f;
    if (t < 60) {
      const float4* r1 = reinterpret_cast<const float4*>(We1 + t * 128);
      const float4* r2 = reinterpret_cast<const float4*>(We2 + t * 128);
      const float4* a1 = reinterpret_cast<const float4*>(ae1);
      const float4* a2 = reinterpret_cast<const float4*>(ae2);
      for (int i = 0; i < 32; ++i) {
        float4 x1 = r1[i], y1 = a1[i];
        float4 x2 = r2[i], y2 = a2[i];
        s1 += x1.x*y1.x + x1.y*y1.y + x1.z*y1.z + x1.w*y1.w;
        s2 += x2.x*y2.x + x2.y*y2.y + x2.z*y2.z + x2.w*y2.w;
      }
    }
    we1[t] = s1; we2[t] = s2;
  } else if (b <= 128) {
    int idx = (b - 1) * 256 + t;            // K=256: 32768 elems
    int k = idx >> 7, n = idx & 127;
    W1t[(size_t)n * 256 + k] = f2bf(W1[idx]);
  } else {
    int idx = (b - 129) * 256 + t;          // K=128: 16384 elems
    int k = idx >> 7, n = idx & 127;
    W2t[(size_t)n * 128 + k] = f2bf(W2[idx]);
  }
}

// single-block exclusive scan body (1024 threads); wave shfl_up scans, 2 barriers
__device__ __forceinline__ void scan_body(const int* __restrict__ degi, int* __restrict__ rowptr,
                                          int N, int E) {
  __shared__ int wsums[16];
  int t = threadIdx.x;
  int wave = t >> 6, lane = t & 63;
  const int CH = 52;                 // 13 * int4 ; 1024*52 = 53248 >= N
  int lo = t * CH;
  int v[52];
  int s = 0;
  #pragma unroll
  for (int i = 0; i < 13; ++i) {
    int base_i = lo + 4 * i;
    if (base_i + 4 <= N) {
      int4 q = *reinterpret_cast<const int4*>(degi + base_i);
      v[4*i+0] = q.x; v[4*i+1] = q.y; v[4*i+2] = q.z; v[4*i+3] = q.w;
      s += q.x + q.y + q.z + q.w;
    } else {
      #pragma unroll
      for (int j = 0; j < 4; ++j) {
        int idx = base_i + j;
        int x = (idx < N) ? degi[idx] : 0;
        v[4*i+j] = x; s += x;
      }
    }
  }
  int inc = s;
  #pragma unroll
  for (int off = 1; off < 64; off <<= 1) {
    int u = __shfl_up(inc, off);
    if (lane >= off) inc += u;
  }
  if (lane == 63) wsums[wave] = inc;
  __syncthreads();
  if (wave == 0) {
    int ws = (lane < 16) ? wsums[lane] : 0;
    #pragma unroll
    for (int off = 1; off < 16; off <<= 1) {
      int u = __shfl_up(ws, off);
      if (lane >= off) ws += u;
    }
    if (lane < 16) wsums[lane] = ws;
  }
  __syncthreads();
  int base = inc - s + (wave ? wsums[wave - 1] : 0);
  #pragma unroll
  for (int i = 0; i < 13; ++i) {
    int base_i = lo + 4 * i;
    if (base_i + 4 <= N) {
      int4 o;
      o.x = base; base += v[4*i+0];
      o.y = base; base += v[4*i+1];
      o.z = base; base += v[4*i+2];
      o.w = base; base += v[4*i+3];
      *reinterpret_cast<int4*>(rowptr + base_i) = o;
    } else {
      #pragma unroll
      for (int j = 0; j < 4; ++j) {
        int idx = base_i + j;
        if (idx < N) { rowptr[idx] = base; base += v[4*i+j]; }
      }
    }
  }
  if (t == 0) rowptr[N] = E;
}

// ---------------- fused scan + streaming e-dot ----------------
__global__ __launch_bounds__(1024) void k_scanedot(const int* __restrict__ degi, int* __restrict__ rowptr,
                       int N, int E,
                       const float* __restrict__ ef,
                       const float* __restrict__ we1, const float* __restrict__ we2,
                       float2* __restrict__ edgeD, int EDOTB) {
  if (blockIdx.x == 0) { scan_body(degi, rowptr, N, E); return; }
  int t = threadIdx.x;
  int sub = t & 3;
  int qw = (int)(blockIdx.x - 1) * 256 + (t >> 2);
  const float4* w1v = reinterpret_cast<const float4*>(we1);
  const float4* w2v = reinterpret_cast<const float4*>(we2);
  float4 wa0 = w1v[sub],     wb0 = w2v[sub];
  float4 wa1 = w1v[sub + 4], wb1 = w2v[sub + 4];
  float4 wa2 = w1v[sub + 8], wb2 = w2v[sub + 8];
  bool has3 = sub < 3;
  float4 wa3 = make_float4(0.f,0.f,0.f,0.f), wb3 = wa3;
  if (has3) { wa3 = w1v[sub + 12]; wb3 = w2v[sub + 12]; }
  const float4* efq = reinterpret_cast<const float4*>(ef);
  int stride = EDOTB * 256;
  for (int e = qw; e < E; e += stride) {
    size_t b = (size_t)e * 15;
    float4 f0 = efq[b + sub];
    float4 f1 = efq[b + sub + 4];
    float4 f2 = efq[b + sub + 8];
    float4 f3 = make_float4(0.f,0.f,0.f,0.f);
    if (has3) f3 = efq[b + sub + 12];
    float d1 = dot4(f0, wa0) + dot4(f1, wa1) + dot4(f2, wa2) + dot4(f3, wa3);
    float d2 = dot4(f0, wb0) + dot4(f1, wb1) + dot4(f2, wb2) + dot4(f3, wb3);
    d1 += __shfl_xor(d1, 1); d1 += __shfl_xor(d1, 2);
    d2 += __shfl_xor(d2, 1); d2 += __shfl_xor(d2, 2);
    if (sub == 0) edgeD[e] = make_float2(d1, d2);
  }
}

// Full-width MFMA GEMM body: one wave computes C[16,128] = A[16,K] @ Bt[128,K]^T.
template <int K, bool AFP32>
__device__ __forceinline__ void gemm_body(int wid, int lane,
    const void* __restrict__ Av, const unsigned short* __restrict__ Bt,
    unsigned short* __restrict__ C,
    const float* __restrict__ a_src, const float* __restrict__ a_dst,
    float* __restrict__ alps, float* __restrict__ alpd, int M) {
  int mt = wid;
  if (mt * 16 >= M) return;
  int r = lane & 15, quad = lane >> 4;
  int m = mt * 16 + r;
  floatx4 acc[8] = {};
  for (int k0 = 0; k0 < K; k0 += 32) {
    int kk = k0 + quad * 8;
    short8 a;
    if (AFP32) {
      const float4* ap = reinterpret_cast<const float4*>((const float*)Av + (size_t)m * K + kk);
      float4 lo = ap[0], hi = ap[1];
      union { short8 v; unsigned short u[8]; } pa;
      pa.u[0]=f2bf(lo.x); pa.u[1]=f2bf(lo.y); pa.u[2]=f2bf(lo.z); pa.u[3]=f2bf(lo.w);
      pa.u[4]=f2bf(hi.x); pa.u[5]=f2bf(hi.y); pa.u[6]=f2bf(hi.z); pa.u[7]=f2bf(hi.w);
      a = pa.v;
    } else {
      a = *reinterpret_cast<const short8*>((const unsigned short*)Av + (size_t)m * K + kk);
    }
    #pragma unroll
    for (int t = 0; t < 8; ++t) {
      short8 b = *reinterpret_cast<const short8*>(Bt + (size_t)(t*16 + r) * K + kk);
      acc[t] = __builtin_amdgcn_mfma_f32_16x16x32_bf16(a, b, acc[t], 0, 0, 0);
    }
  }
  float asv[8], adv[8];
  #pragma unroll
  for (int t = 0; t < 8; ++t) {
    int col = t * 16 + r;
    asv[t] = a_src[col]; adv[t] = a_dst[col];
  }
  #pragma unroll
  for (int rr = 0; rr < 4; ++rr) {
    float ps = 0.f, pd = 0.f;
    #pragma unroll
    for (int t = 0; t < 8; ++t) { ps += acc[t][rr] * asv[t]; pd += acc[t][rr] * adv[t]; }
    #pragma unroll
    for (int mo = 1; mo <= 8; mo <<= 1) { ps += __shfl_xor(ps, mo); pd += __shfl_xor(pd, mo); }
    if (r == 0) {
      int row = mt * 16 + quad * 4 + rr;
      alps[row] = ps;
      alpd[row] = pd;
    }
  }
  #pragma unroll
  for (int t = 0; t < 8; ++t) {
    int col = t * 16 + r;
    #pragma unroll
    for (int rr = 0; rr < 4; ++rr) {
      int row = mt * 16 + quad * 4 + rr;
      C[(size_t)row * 128 + col] = f2bf(acc[t][rr]);
    }
  }
}

template <int K, bool AFP32>
__global__ __launch_bounds__(256) void k_gemm(const void* __restrict__ Av, const unsigned short* __restrict__ Bt,
                                              unsigned short* __restrict__ C,
                                              const float* __restrict__ a_src, const float* __restrict__ a_dst,
                                              float* __restrict__ alps, float* __restrict__ alpd, int M) {
  int wid = (blockIdx.x * 256 + threadIdx.x) >> 6;
  int lane = threadIdx.x & 63;
  gemm_body<K, AFP32>(wid, lane, Av, Bt, C, a_src, a_dst, alps, alpd, M);
}

// ---------------- fused GEMM1 + CSR scatter ----------------
// scatter stores {src, d1, d2, outidx} per record (outidx = e mod half, for decode)
__global__ __launch_bounds__(256) void k_scatgemm(
                       const int* __restrict__ src, const int* __restrict__ dst,
                       const int* __restrict__ eslot, const int* __restrict__ rowptr,
                       const float2* __restrict__ edgeD, float4* __restrict__ csr,
                       int E, int half, int GB,
                       const float* __restrict__ x, const unsigned short* __restrict__ W1t,
                       unsigned short* __restrict__ hA,
                       const float* __restrict__ a_src, const float* __restrict__ a_dst,
                       float* __restrict__ alps, float* __restrict__ alpd, int N) {
  int t = threadIdx.x;
  if (blockIdx.x < (unsigned)GB) {
    int wid = (blockIdx.x * 256 + t) >> 6;
    int lane = t & 63;
    gemm_body<256, true>(wid, lane, x, W1t, hA, a_src, a_dst, alps, alpd, N);
    return;
  }
  int e = (blockIdx.x - GB) * 256 + t;
  if (e >= E) return;
  int d = dst[e];
  float2 dd = edgeD[e];
  int slot = rowptr[d] + eslot[e];
  int outidx = (e < half) ? e : e - half;
  float4 v;
  v.x = __int_as_float(src[e]); v.y = dd.x; v.z = dd.y; v.w = __int_as_float(outidx);
  csr[slot] = v;
}

// online-softmax aggregation; wave per node, 4 edge streams (quarter-wave each),
// lane owns 8 channels (uint4 = 8 bf16); 3-deep csr pipeline + 2-deep (as_,h) gathers.
// Defer-max: rescale only when new alpha exceeds running max by >8 (e^8 headroom).
__global__ __launch_bounds__(256) void k_agg(const int* __restrict__ rowptr, const float4* __restrict__ csr,
                      const float* __restrict__ as_, const float* __restrict__ ad_,
                      const unsigned short* __restrict__ h, const float* __restrict__ bias,
                      unsigned short* __restrict__ out, int N, int use2, int do_relu) {
  int i = (blockIdx.x * blockDim.x + threadIdx.x) >> 6;
  int lane = threadIdx.x & 63;
  if (i >= N) return;
  int st = lane >> 4;       // stream 0..3
  int q  = lane & 15;       // channel group: ch [8q, 8q+8)
  int start = rowptr[i], end = rowptr[i + 1];
  int cnt = end - start;
  float adi = ad_[i], asi = as_[i];
  float m = -3.0e38f, s = 0.f, esum = 0.f;
  float acc[8] = {};
  int idx = start + st;
  float4 cur, nx1, nx2;
  float as_c = 0.f, as_1 = 0.f;
  uint4 hv_c, hv_1;
  if (idx < end) cur = csr[idx];
  if (idx + 4 < end) nx1 = csr[idx + 4];
  if (idx + 8 < end) nx2 = csr[idx + 8];
  if (idx < end) {
    int sv = __float_as_int(cur.x);
    as_c = as_[sv];
    hv_c = *reinterpret_cast<const uint4*>(h + (size_t)sv * 128 + q * 8);
  }
  if (idx + 4 < end) {
    int sv = __float_as_int(nx1.x);
    as_1 = as_[sv];
    hv_1 = *reinterpret_cast<const uint4*>(h + (size_t)sv * 128 + q * 8);
  }
  for (; idx < end; idx += 4) {
    float4 n3;
    if (idx + 12 < end) n3 = csr[idx + 12];
    float as_2 = 0.f; uint4 hv_2;
    if (idx + 8 < end) {
      int sv = __float_as_int(nx2.x);
      as_2 = as_[sv];
      hv_2 = *reinterpret_cast<const uint4*>(h + (size_t)sv * 128 + q * 8);
    }
    float e = use2 ? cur.z : cur.y;
    float a = lrelu(as_c + adi + e);
    esum += e;
    if (a > m + 8.f) {
      float rr = __expf(m - a);
      s *= rr;
      #pragma unroll
      for (int j = 0; j < 8; ++j) acc[j] *= rr;
      m = a;
    }
    float w = __expf(a - m);
    s += w;
    acc[0] += w * bflo(hv_c.x); acc[1] += w * bfhi(hv_c.x);
    acc[2] += w * bflo(hv_c.y); acc[3] += w * bfhi(hv_c.y);
    acc[4] += w * bflo(hv_c.z); acc[5] += w * bfhi(hv_c.z);
    acc[6] += w * bflo(hv_c.w); acc[7] += w * bfhi(hv_c.w);
    cur = nx1; nx1 = nx2; nx2 = n3;
    as_c = as_1; hv_c = hv_1;
    as_1 = as_2; hv_1 = hv_2;
  }
  // merge 4 streams: xor 16 then xor 32
  #pragma unroll
  for (int off = 16; off <= 32; off <<= 1) {
    float m_o = __shfl_xor(m, off);
    float s_o = __shfl_xor(s, off);
    float e_o = __shfl_xor(esum, off);
    float ao[8];
    #pragma unroll
    for (int j = 0; j < 8; ++j) ao[j] = __shfl_xor(acc[j], off);
    float Mn = fmaxf(m, m_o);
    float f  = __expf(m - Mn), fo = __expf(m_o - Mn);
    s = s * f + s_o * fo;
    #pragma unroll
    for (int j = 0; j < 8; ++j) acc[j] = acc[j] * f + ao[j] * fo;
    esum += e_o;
    m = Mn;
  }
  // merge self-loop
  float a_self = lrelu(asi + adi + esum / fmaxf((float)cnt, 1.f));
  float M2 = fmaxf(m, a_self);
  float g = __expf(m - M2);
  float w_self = __expf(a_self - M2);
  s = s * g + w_self;
  uint4 hs = *reinterpret_cast<const uint4*>(h + (size_t)i * 128 + q * 8);
  float hsf[8] = { bflo(hs.x), bfhi(hs.x), bflo(hs.y), bfhi(hs.y),
                   bflo(hs.z), bfhi(hs.z), bflo(hs.w), bfhi(hs.w) };
  #pragma unroll
  for (int j = 0; j < 8; ++j) acc[j] = acc[j] * g + w_self * hsf[j];
  float inv = 1.0f / s;
  float4 bv0 = *reinterpret_cast<const float4*>(bias + q * 8);
  float4 bv1 = *reinterpret_cast<const float4*>(bias + q * 8 + 4);
  float o[8];
  o[0] = acc[0]*inv + bv0.x; o[1] = acc[1]*inv + bv0.y;
  o[2] = acc[2]*inv + bv0.z; o[3] = acc[3]*inv + bv0.w;
  o[4] = acc[4]*inv + bv1.x; o[5] = acc[5]*inv + bv1.y;
  o[6] = acc[6]*inv + bv1.z; o[7] = acc[7]*inv + bv1.w;
  if (do_relu) {
    #pragma unroll
    for (int j = 0; j < 8; ++j) o[j] = fmaxf(o[j], 0.f);
  }
  if (st == 0) {
    uint4 ov;
    ov.x = (unsigned)f2bf(o[0]) | ((unsigned)f2bf(o[1]) << 16);
    ov.y = (unsigned)f2bf(o[2]) | ((unsigned)f2bf(o[3]) << 16);
    ov.z = (unsigned)f2bf(o[4]) | ((unsigned)f2bf(o[5]) << 16);
    ov.w = (unsigned)f2bf(o[6]) | ((unsigned)f2bf(o[7]) << 16);
    *reinterpret_cast<uint4*>(out + (size_t)i * 128 + q * 8) = ov;
  }
}

// CSR-order decode: wave per node; z[i] (dst row) loaded ONCE into registers;
// per edge: csr record gives src + outidx; gather z[src], dot, atomicAdd to out.
// Halves random-gather bytes vs edge-order decode (z[dst] now sequential).
__global__ __launch_bounds__(256) void k_decode_csr(const int* __restrict__ rowptr,
                         const float4* __restrict__ csr,
                         const unsigned short* __restrict__ z,
                         float* __restrict__ out, int N) {
  int i = (blockIdx.x * blockDim.x + threadIdx.x) >> 6;
  int lane = threadIdx.x & 63;
  if (i >= N) return;
  int st = lane >> 4;       // stream 0..3
  int q  = lane & 15;       // channel group: ch [8q, 8q+8)
  int start = rowptr[i], end = rowptr[i + 1];
  uint4 zi = *reinterpret_cast<const uint4*>(z + (size_t)i * 128 + q * 8);
  float zf[8] = { bflo(zi.x), bfhi(zi.x), bflo(zi.y), bfhi(zi.y),
                  bflo(zi.z), bfhi(zi.z), bflo(zi.w), bfhi(zi.w) };
  int idx = start + st;
  float4 cur, nx1, nx2;
  uint4 zv_c, zv_1;
  if (idx < end) cur = csr[idx];
  if (idx + 4 < end) nx1 = csr[idx + 4];
  if (idx + 8 < end) nx2 = csr[idx + 8];
  if (idx < end) {
    int sv = __float_as_int(cur.x);
    zv_c = *reinterpret_cast<const uint4*>(z + (size_t)sv * 128 + q * 8);
  }
  if (idx + 4 < end) {
    int sv = __float_as_int(nx1.x);
    zv_1 = *reinterpret_cast<const uint4*>(z + (size_t)sv * 128 + q * 8);
  }
  for (; idx < end; idx += 4) {
    float4 n3;
    if (idx + 12 < end) n3 = csr[idx + 12];
    uint4 zv_2;
    if (idx + 8 < end) {
      int sv = __float_as_int(nx2.x);
      zv_2 = *reinterpret_cast<const uint4*>(z + (size_t)sv * 128 + q * 8);
    }
    float p = zf[0]*bflo(zv_c.x) + zf[1]*bfhi(zv_c.x)
            + zf[2]*bflo(zv_c.y) + zf[3]*bfhi(zv_c.y)
            + zf[4]*bflo(zv_c.z) + zf[5]*bfhi(zv_c.z)
            + zf[6]*bflo(zv_c.w) + zf[7]*bfhi(zv_c.w);
    p += __shfl_xor(p, 1);
    p += __shfl_xor(p, 2);
    p += __shfl_xor(p, 4);
    p += __shfl_xor(p, 8);
    if (q == 0) atomicAdd(out + __float_as_int(cur.w), p);
    cur = nx1; nx1 = nx2; nx2 = n3;
    zv_c = zv_1; zv_1 = zv_2;
  }
}

extern "C" void kernel_launch(void* const* d_in, const int* in_sizes, int n_in,
                              void* d_out, int out_size, void* d_ws, size_t ws_size,
                              hipStream_t stream) {
  const int H = 128;
  const int N = in_sizes[0] / 256;        // 50000
  const int E = in_sizes[1] / 2;          // 800000
  const int half = E / 2;

  const float* x   = (const float*)d_in[0];
  const int* eidx  = (const int*)d_in[1];
  const float* ef  = (const float*)d_in[2];
  const float* W1  = (const float*)d_in[4];
  const float* as1 = (const float*)d_in[5];
  const float* ad1 = (const float*)d_in[6];
  const float* We1 = (const float*)d_in[7];
  const float* ae1 = (const float*)d_in[8];
  const float* b1  = (const float*)d_in[9];
  const float* W2  = (const float*)d_in[10];
  const float* as2 = (const float*)d_in[11];
  const float* ad2 = (const float*)d_in[12];
  const float* We2 = (const float*)d_in[13];
  const float* ae2 = (const float*)d_in[14];
  const float* b2  = (const float*)d_in[15];

  const int* src = eidx;
  const int* dst = eidx + E;

  size_t off = 0;
  auto alloc = [&](size_t bytes) -> void* {
    void* p = (char*)d_ws + off;
    off += (bytes + 255) & ~(size_t)255;
    return p;
  };
  float*  we1    = (float*)alloc(64 * 4);
  float*  we2    = (float*)alloc(64 * 4);
  int*    degi   = (int*)alloc((size_t)N * 4);
  float*  alps   = (float*)alloc((size_t)N * 4);
  float*  alpd   = (float*)alloc((size_t)N * 4);
  int*    eslot  = (int*)alloc((size_t)E * 4);
  int*    rowptr = (int*)alloc((size_t)(N + 1) * 4);
  float2* edgeD  = (float2*)alloc((size_t)E * 8);
  float4* csr    = (float4*)alloc((size_t)E * 16);
  unsigned short* W1t = (unsigned short*)alloc((size_t)128 * 256 * 2);
  unsigned short* W2t = (unsigned short*)alloc((size_t)128 * 128 * 2);
  unsigned short* hA  = (unsigned short*)alloc((size_t)N * H * 2);
  unsigned short* hB  = (unsigned short*)alloc((size_t)N * H * 2);

  hipMemsetAsync(degi, 0, (size_t)N * 4, stream);
  hipMemsetAsync(d_out, 0, (size_t)out_size, stream);

  int CB = (E + 255) / 256;                         // count blocks
  k_prep<<<CB + 193, 256, 0, stream>>>(dst, degi, eslot, E, CB,
                                       We1, ae1, We2, ae2, we1, we2, W1, W1t, W2, W2t);

  // ---- scan (1 block) overlapped with streaming e-dot ----
  int EDOTB = 782;
  k_scanedot<<<1 + EDOTB, 1024, 0, stream>>>(degi, rowptr, N, E, ef, we1, we2, edgeD, EDOTB);

  int gwaves = (N + 15) / 16;                       // full-width waves
  int GB = (gwaves + 3) / 4;
  int SB = (E + 255) / 256;
  // ---- layer 1 GEMM (+alpha) overlapped with CSR scatter ----
  k_scatgemm<<<GB + SB, 256, 0, stream>>>(src, dst, eslot, rowptr, edgeD, csr, E, half, GB,
                                          x, W1t, hA, as1, ad1, alps, alpd, N);
  k_agg<<<(N + 3) / 4, 256, 0, stream>>>(rowptr, csr, alps, alpd, hA, b1, hB, N, 0, 1);
  // ---- layer 2 ----
  k_gemm<128, false><<<GB, 256, 0, stream>>>(hB, W2t, hA, as2, ad2, alps, alpd, N);
  k_agg<<<(N + 3) / 4, 256, 0, stream>>>(rowptr, csr, alps, alpd, hA, b2, hB, N, 1, 0);
  // ---- decode (CSR-order, z[dst] row resident per wave) ----
  k_decode_csr<<<(N + 3) / 4, 256, 0, stream>>>(rowptr, csr, hB, (float*)d_out, N);
}

// Round 9
// 558.064 us; speedup vs baseline: 1.0849x; 1.0092x over previous
//
#include <hip/hip_runtime.h>
#include <hip/hip_bf16.h>

typedef __attribute__((ext_vector_type(8))) short short8;
typedef __attribute__((ext_vector_type(4))) float floatx4;

__device__ __forceinline__ float lrelu(float a){ return a > 0.f ? a : 0.2f * a; }
__device__ __forceinline__ float bflo(unsigned u){ return __uint_as_float(u << 16); }
__device__ __forceinline__ float bfhi(unsigned u){ return __uint_as_float(u & 0xffff0000u); }
__device__ __forceinline__ unsigned short f2bf(float f){
  __hip_bfloat16 h = __float2bfloat16(f);
  return *reinterpret_cast<unsigned short*>(&h);
}
__device__ __forceinline__ float dot4(float4 a, float4 b){
  return a.x*b.x + a.y*b.y + a.z*b.z + a.w*b.w;
}

// ---------------- mega-prep: e-dot stream + dst-count atomics + W transposes ----
// blocks [0, EDOTB): streaming e-dot; each block self-computes we1/we2 into LDS
//   (removes cross-block dependency; We/ae are L2-resident, 7.7K MACs/block)
// blocks [EDOTB, EDOTB+CB): per-edge slot within dst bucket (atomics into degi)
// blocks [EDOTB+CB, +128): W1t transpose ; next 64: W2t transpose
__global__ __launch_bounds__(256) void k_prep(
                       const int* __restrict__ dst, int* __restrict__ degi,
                       int* __restrict__ eslot, int E, int EDOTB, int CB,
                       const float* __restrict__ We1, const float* __restrict__ ae1,
                       const float* __restrict__ We2, const float* __restrict__ ae2,
                       const float* __restrict__ ef, float2* __restrict__ edgeD,
                       const float* __restrict__ W1, unsigned short* __restrict__ W1t,
                       const float* __restrict__ W2, unsigned short* __restrict__ W2t) {
  int t = threadIdx.x;
  unsigned b = blockIdx.x;
  if (b < (unsigned)EDOTB) {
    __shared__ float4 lw1v[16], lw2v[16];
    float* lw1 = reinterpret_cast<float*>(lw1v);
    float* lw2 = reinterpret_cast<float*>(lw2v);
    if (t < 64) {
      float s = 0.f;
      if (t < 60) {
        const float4* r = reinterpret_cast<const float4*>(We1 + t * 128);
        const float4* a = reinterpret_cast<const float4*>(ae1);
        for (int i = 0; i < 32; ++i) { float4 x = r[i], y = a[i];
          s += x.x*y.x + x.y*y.y + x.z*y.z + x.w*y.w; }
      }
      lw1[t] = s;
    } else if (t < 128) {
      int k = t - 64;
      float s = 0.f;
      if (k < 60) {
        const float4* r = reinterpret_cast<const float4*>(We2 + k * 128);
        const float4* a = reinterpret_cast<const float4*>(ae2);
        for (int i = 0; i < 32; ++i) { float4 x = r[i], y = a[i];
          s += x.x*y.x + x.y*y.y + x.z*y.z + x.w*y.w; }
      }
      lw2[k] = s;
    }
    __syncthreads();
    int sub = t & 3;
    int qg = (int)b * 64 + (t >> 2);
    float4 wa0 = lw1v[sub],     wb0 = lw2v[sub];
    float4 wa1 = lw1v[sub + 4], wb1 = lw2v[sub + 4];
    float4 wa2 = lw1v[sub + 8], wb2 = lw2v[sub + 8];
    bool has3 = sub < 3;
    float4 wa3 = make_float4(0.f,0.f,0.f,0.f), wb3 = wa3;
    if (has3) { wa3 = lw1v[sub + 12]; wb3 = lw2v[sub + 12]; }
    const float4* efq = reinterpret_cast<const float4*>(ef);
    int stride = EDOTB * 64;
    for (int e = qg; e < E; e += stride) {
      size_t bb = (size_t)e * 15;
      float4 f0 = efq[bb + sub];
      float4 f1 = efq[bb + sub + 4];
      float4 f2 = efq[bb + sub + 8];
      float4 f3 = make_float4(0.f,0.f,0.f,0.f);
      if (has3) f3 = efq[bb + sub + 12];
      float d1 = dot4(f0, wa0) + dot4(f1, wa1) + dot4(f2, wa2) + dot4(f3, wa3);
      float d2 = dot4(f0, wb0) + dot4(f1, wb1) + dot4(f2, wb2) + dot4(f3, wb3);
      d1 += __shfl_xor(d1, 1); d1 += __shfl_xor(d1, 2);
      d2 += __shfl_xor(d2, 1); d2 += __shfl_xor(d2, 2);
      if (sub == 0) edgeD[e] = make_float2(d1, d2);
    }
    return;
  }
  if (b < (unsigned)(EDOTB + CB)) {
    int e = (b - EDOTB) * 256 + t;
    if (e < E) eslot[e] = atomicAdd(degi + dst[e], 1);
    return;
  }
  int bb = b - EDOTB - CB;
  if (bb < 128) {
    int idx = bb * 256 + t;                 // K=256: 32768 elems
    int k = idx >> 7, n = idx & 127;
    W1t[(size_t)n * 256 + k] = f2bf(W1[idx]);
  } else {
    int idx = (bb - 128) * 256 + t;         // K=128: 16384 elems
    int k = idx >> 7, n = idx & 127;
    W2t[(size_t)n * 128 + k] = f2bf(W2[idx]);
  }
}

// single-block exclusive scan (1024 threads); wave shfl_up scans, 2 barriers
__global__ __launch_bounds__(1024) void k_scan(const int* __restrict__ degi, int* __restrict__ rowptr,
                                               int N, int E) {
  __shared__ int wsums[16];
  int t = threadIdx.x;
  int wave = t >> 6, lane = t & 63;
  const int CH = 52;                 // 13 * int4 ; 1024*52 = 53248 >= N
  int lo = t * CH;
  int v[52];
  int s = 0;
  #pragma unroll
  for (int i = 0; i < 13; ++i) {
    int base_i = lo + 4 * i;
    if (base_i + 4 <= N) {
      int4 q = *reinterpret_cast<const int4*>(degi + base_i);
      v[4*i+0] = q.x; v[4*i+1] = q.y; v[4*i+2] = q.z; v[4*i+3] = q.w;
      s += q.x + q.y + q.z + q.w;
    } else {
      #pragma unroll
      for (int j = 0; j < 4; ++j) {
        int idx = base_i + j;
        int x = (idx < N) ? degi[idx] : 0;
        v[4*i+j] = x; s += x;
      }
    }
  }
  int inc = s;
  #pragma unroll
  for (int off = 1; off < 64; off <<= 1) {
    int u = __shfl_up(inc, off);
    if (lane >= off) inc += u;
  }
  if (lane == 63) wsums[wave] = inc;
  __syncthreads();
  if (wave == 0) {
    int ws = (lane < 16) ? wsums[lane] : 0;
    #pragma unroll
    for (int off = 1; off < 16; off <<= 1) {
      int u = __shfl_up(ws, off);
      if (lane >= off) ws += u;
    }
    if (lane < 16) wsums[lane] = ws;
  }
  __syncthreads();
  int base = inc - s + (wave ? wsums[wave - 1] : 0);
  #pragma unroll
  for (int i = 0; i < 13; ++i) {
    int base_i = lo + 4 * i;
    if (base_i + 4 <= N) {
      int4 o;
      o.x = base; base += v[4*i+0];
      o.y = base; base += v[4*i+1];
      o.z = base; base += v[4*i+2];
      o.w = base; base += v[4*i+3];
      *reinterpret_cast<int4*>(rowptr + base_i) = o;
    } else {
      #pragma unroll
      for (int j = 0; j < 4; ++j) {
        int idx = base_i + j;
        if (idx < N) { rowptr[idx] = base; base += v[4*i+j]; }
      }
    }
  }
  if (t == 0) rowptr[N] = E;
}

// Full-width MFMA GEMM body: one wave computes C[16,128] = A[16,K] @ Bt[128,K]^T.
template <int K, bool AFP32>
__device__ __forceinline__ void gemm_body(int wid, int lane,
    const void* __restrict__ Av, const unsigned short* __restrict__ Bt,
    unsigned short* __restrict__ C,
    const float* __restrict__ a_src, const float* __restrict__ a_dst,
    float* __restrict__ alps, float* __restrict__ alpd, int M) {
  int mt = wid;
  if (mt * 16 >= M) return;
  int r = lane & 15, quad = lane >> 4;
  int m = mt * 16 + r;
  floatx4 acc[8] = {};
  for (int k0 = 0; k0 < K; k0 += 32) {
    int kk = k0 + quad * 8;
    short8 a;
    if (AFP32) {
      const float4* ap = reinterpret_cast<const float4*>((const float*)Av + (size_t)m * K + kk);
      float4 lo = ap[0], hi = ap[1];
      union { short8 v; unsigned short u[8]; } pa;
      pa.u[0]=f2bf(lo.x); pa.u[1]=f2bf(lo.y); pa.u[2]=f2bf(lo.z); pa.u[3]=f2bf(lo.w);
      pa.u[4]=f2bf(hi.x); pa.u[5]=f2bf(hi.y); pa.u[6]=f2bf(hi.z); pa.u[7]=f2bf(hi.w);
      a = pa.v;
    } else {
      a = *reinterpret_cast<const short8*>((const unsigned short*)Av + (size_t)m * K + kk);
    }
    #pragma unroll
    for (int t = 0; t < 8; ++t) {
      short8 b = *reinterpret_cast<const short8*>(Bt + (size_t)(t*16 + r) * K + kk);
      acc[t] = __builtin_amdgcn_mfma_f32_16x16x32_bf16(a, b, acc[t], 0, 0, 0);
    }
  }
  float asv[8], adv[8];
  #pragma unroll
  for (int t = 0; t < 8; ++t) {
    int col = t * 16 + r;
    asv[t] = a_src[col]; adv[t] = a_dst[col];
  }
  #pragma unroll
  for (int rr = 0; rr < 4; ++rr) {
    float ps = 0.f, pd = 0.f;
    #pragma unroll
    for (int t = 0; t < 8; ++t) { ps += acc[t][rr] * asv[t]; pd += acc[t][rr] * adv[t]; }
    #pragma unroll
    for (int mo = 1; mo <= 8; mo <<= 1) { ps += __shfl_xor(ps, mo); pd += __shfl_xor(pd, mo); }
    if (r == 0) {
      int row = mt * 16 + quad * 4 + rr;
      alps[row] = ps;
      alpd[row] = pd;
    }
  }
  #pragma unroll
  for (int t = 0; t < 8; ++t) {
    int col = t * 16 + r;
    #pragma unroll
    for (int rr = 0; rr < 4; ++rr) {
      int row = mt * 16 + quad * 4 + rr;
      C[(size_t)row * 128 + col] = f2bf(acc[t][rr]);
    }
  }
}

template <int K, bool AFP32>
__global__ __launch_bounds__(256) void k_gemm(const void* __restrict__ Av, const unsigned short* __restrict__ Bt,
                                              unsigned short* __restrict__ C,
                                              const float* __restrict__ a_src, const float* __restrict__ a_dst,
                                              float* __restrict__ alps, float* __restrict__ alpd, int M) {
  int wid = (blockIdx.x * 256 + threadIdx.x) >> 6;
  int lane = threadIdx.x & 63;
  gemm_body<K, AFP32>(wid, lane, Av, Bt, C, a_src, a_dst, alps, alpd, M);
}

// ---------------- fused GEMM1 + CSR scatter ----------------
__global__ __launch_bounds__(256) void k_scatgemm(
                       const int* __restrict__ src, const int* __restrict__ dst,
                       const int* __restrict__ eslot, const int* __restrict__ rowptr,
                       const float2* __restrict__ edgeD, float4* __restrict__ csr,
                       int E, int GB,
                       const float* __restrict__ x, const unsigned short* __restrict__ W1t,
                       unsigned short* __restrict__ hA,
                       const float* __restrict__ a_src, const float* __restrict__ a_dst,
                       float* __restrict__ alps, float* __restrict__ alpd, int N) {
  int t = threadIdx.x;
  if (blockIdx.x < (unsigned)GB) {
    int wid = (blockIdx.x * 256 + t) >> 6;
    int lane = t & 63;
    gemm_body<256, true>(wid, lane, x, W1t, hA, a_src, a_dst, alps, alpd, N);
    return;
  }
  int e = (blockIdx.x - GB) * 256 + t;
  if (e >= E) return;
  int d = dst[e];
  float2 dd = edgeD[e];
  int slot = rowptr[d] + eslot[e];
  float4 v;
  v.x = __int_as_float(src[e]); v.y = dd.x; v.z = dd.y; v.w = 0.f;
  csr[slot] = v;
}

// online-softmax aggregation; wave per node, 4 edge streams (quarter-wave each),
// lane owns 8 channels (uint4 = 8 bf16); 3-deep csr pipeline + 2-deep (as_,h) gathers.
// Defer-max: rescale only when new alpha exceeds running max by >8 (e^8 headroom).
__global__ __launch_bounds__(256) void k_agg(const int* __restrict__ rowptr, const float4* __restrict__ csr,
                      const float* __restrict__ as_, const float* __restrict__ ad_,
                      const unsigned short* __restrict__ h, const float* __restrict__ bias,
                      unsigned short* __restrict__ out, int N, int use2, int do_relu) {
  int i = (blockIdx.x * blockDim.x + threadIdx.x) >> 6;
  int lane = threadIdx.x & 63;
  if (i >= N) return;
  int st = lane >> 4;       // stream 0..3
  int q  = lane & 15;       // channel group: ch [8q, 8q+8)
  int start = rowptr[i], end = rowptr[i + 1];
  int cnt = end - start;
  float adi = ad_[i], asi = as_[i];
  float m = -3.0e38f, s = 0.f, esum = 0.f;
  float acc[8] = {};
  int idx = start + st;
  float4 cur, nx1, nx2;
  float as_c = 0.f, as_1 = 0.f;
  uint4 hv_c, hv_1;
  if (idx < end) cur = csr[idx];
  if (idx + 4 < end) nx1 = csr[idx + 4];
  if (idx + 8 < end) nx2 = csr[idx + 8];
  if (idx < end) {
    int sv = __float_as_int(cur.x);
    as_c = as_[sv];
    hv_c = *reinterpret_cast<const uint4*>(h + (size_t)sv * 128 + q * 8);
  }
  if (idx + 4 < end) {
    int sv = __float_as_int(nx1.x);
    as_1 = as_[sv];
    hv_1 = *reinterpret_cast<const uint4*>(h + (size_t)sv * 128 + q * 8);
  }
  for (; idx < end; idx += 4) {
    float4 n3;
    if (idx + 12 < end) n3 = csr[idx + 12];
    float as_2 = 0.f; uint4 hv_2;
    if (idx + 8 < end) {
      int sv = __float_as_int(nx2.x);
      as_2 = as_[sv];
      hv_2 = *reinterpret_cast<const uint4*>(h + (size_t)sv * 128 + q * 8);
    }
    float e = use2 ? cur.z : cur.y;
    float a = lrelu(as_c + adi + e);
    esum += e;
    if (a > m + 8.f) {
      float rr = __expf(m - a);
      s *= rr;
      #pragma unroll
      for (int j = 0; j < 8; ++j) acc[j] *= rr;
      m = a;
    }
    float w = __expf(a - m);
    s += w;
    acc[0] += w * bflo(hv_c.x); acc[1] += w * bfhi(hv_c.x);
    acc[2] += w * bflo(hv_c.y); acc[3] += w * bfhi(hv_c.y);
    acc[4] += w * bflo(hv_c.z); acc[5] += w * bfhi(hv_c.z);
    acc[6] += w * bflo(hv_c.w); acc[7] += w * bfhi(hv_c.w);
    cur = nx1; nx1 = nx2; nx2 = n3;
    as_c = as_1; hv_c = hv_1;
    as_1 = as_2; hv_1 = hv_2;
  }
  // merge 4 streams: xor 16 then xor 32
  #pragma unroll
  for (int off = 16; off <= 32; off <<= 1) {
    float m_o = __shfl_xor(m, off);
    float s_o = __shfl_xor(s, off);
    float e_o = __shfl_xor(esum, off);
    float ao[8];
    #pragma unroll
    for (int j = 0; j < 8; ++j) ao[j] = __shfl_xor(acc[j], off);
    float Mn = fmaxf(m, m_o);
    float f  = __expf(m - Mn), fo = __expf(m_o - Mn);
    s = s * f + s_o * fo;
    #pragma unroll
    for (int j = 0; j < 8; ++j) acc[j] = acc[j] * f + ao[j] * fo;
    esum += e_o;
    m = Mn;
  }
  // merge self-loop
  float a_self = lrelu(asi + adi + esum / fmaxf((float)cnt, 1.f));
  float M2 = fmaxf(m, a_self);
  float g = __expf(m - M2);
  float w_self = __expf(a_self - M2);
  s = s * g + w_self;
  uint4 hs = *reinterpret_cast<const uint4*>(h + (size_t)i * 128 + q * 8);
  float hsf[8] = { bflo(hs.x), bfhi(hs.x), bflo(hs.y), bfhi(hs.y),
                   bflo(hs.z), bfhi(hs.z), bflo(hs.w), bfhi(hs.w) };
  #pragma unroll
  for (int j = 0; j < 8; ++j) acc[j] = acc[j] * g + w_self * hsf[j];
  float inv = 1.0f / s;
  float4 bv0 = *reinterpret_cast<const float4*>(bias + q * 8);
  float4 bv1 = *reinterpret_cast<const float4*>(bias + q * 8 + 4);
  float o[8];
  o[0] = acc[0]*inv + bv0.x; o[1] = acc[1]*inv + bv0.y;
  o[2] = acc[2]*inv + bv0.z; o[3] = acc[3]*inv + bv0.w;
  o[4] = acc[4]*inv + bv1.x; o[5] = acc[5]*inv + bv1.y;
  o[6] = acc[6]*inv + bv1.z; o[7] = acc[7]*inv + bv1.w;
  if (do_relu) {
    #pragma unroll
    for (int j = 0; j < 8; ++j) o[j] = fmaxf(o[j], 0.f);
  }
  if (st == 0) {
    uint4 ov;
    ov.x = (unsigned)f2bf(o[0]) | ((unsigned)f2bf(o[1]) << 16);
    ov.y = (unsigned)f2bf(o[2]) | ((unsigned)f2bf(o[3]) << 16);
    ov.z = (unsigned)f2bf(o[4]) | ((unsigned)f2bf(o[5]) << 16);
    ov.w = (unsigned)f2bf(o[6]) | ((unsigned)f2bf(o[7]) << 16);
    *reinterpret_cast<uint4*>(out + (size_t)i * 128 + q * 8) = ov;
  }
}

// decode: wave handles 4 k's; 8-lane group per (k, half); lane owns 16 channels (2x uint4)
__global__ void k_decode(const int* __restrict__ src, const int* __restrict__ dst,
                         const unsigned short* __restrict__ z, float* __restrict__ out, int halfE) {
  int w = (blockIdx.x * blockDim.x + threadIdx.x) >> 6;
  int lane = threadIdx.x & 63;
  int k0 = w * 4;
  if (k0 >= halfE) return;
  int g = lane >> 3;           // 0..7 : r = g>>1 (k index), hh = g&1 (half)
  int q = lane & 7;            // channel group: shorts [16q, 16q+16)
  int r = g >> 1, hh = g & 1;
  int k = k0 + r;
  float p = 0.f;
  if (k < halfE) {
    int e = k + hh * halfE;
    int sv = src[e], dv = dst[e];
    const uint4* za = reinterpret_cast<const uint4*>(z + (size_t)sv * 128 + q * 16);
    const uint4* zb = reinterpret_cast<const uint4*>(z + (size_t)dv * 128 + q * 16);
    uint4 a0 = za[0], a1 = za[1];
    uint4 b0 = zb[0], b1 = zb[1];
    p = bflo(a0.x)*bflo(b0.x) + bfhi(a0.x)*bfhi(b0.x)
      + bflo(a0.y)*bflo(b0.y) + bfhi(a0.y)*bfhi(b0.y)
      + bflo(a0.z)*bflo(b0.z) + bfhi(a0.z)*bfhi(b0.z)
      + bflo(a0.w)*bflo(b0.w) + bfhi(a0.w)*bfhi(b0.w)
      + bflo(a1.x)*bflo(b1.x) + bfhi(a1.x)*bfhi(b1.x)
      + bflo(a1.y)*bflo(b1.y) + bfhi(a1.y)*bfhi(b1.y)
      + bflo(a1.z)*bflo(b1.z) + bfhi(a1.z)*bfhi(b1.z)
      + bflo(a1.w)*bflo(b1.w) + bfhi(a1.w)*bfhi(b1.w);
  }
  p += __shfl_xor(p, 1);
  p += __shfl_xor(p, 2);
  p += __shfl_xor(p, 4);       // sum over q within the 8-lane group
  p += __shfl_xor(p, 8);       // add the other half (hh)
  if ((lane & 15) == 0) {
    int kk = k0 + (lane >> 4);
    if (kk < halfE) out[kk] = p;   // 4 consecutive 4B stores -> one transaction
  }
}

extern "C" void kernel_launch(void* const* d_in, const int* in_sizes, int n_in,
                              void* d_out, int out_size, void* d_ws, size_t ws_size,
                              hipStream_t stream) {
  const int H = 128;
  const int N = in_sizes[0] / 256;        // 50000
  const int E = in_sizes[1] / 2;          // 800000
  const int half = E / 2;

  const float* x   = (const float*)d_in[0];
  const int* eidx  = (const int*)d_in[1];
  const float* ef  = (const float*)d_in[2];
  const float* W1  = (const float*)d_in[4];
  const float* as1 = (const float*)d_in[5];
  const float* ad1 = (const float*)d_in[6];
  const float* We1 = (const float*)d_in[7];
  const float* ae1 = (const float*)d_in[8];
  const float* b1  = (const float*)d_in[9];
  const float* W2  = (const float*)d_in[10];
  const float* as2 = (const float*)d_in[11];
  const float* ad2 = (const float*)d_in[12];
  const float* We2 = (const float*)d_in[13];
  const float* ae2 = (const float*)d_in[14];
  const float* b2  = (const float*)d_in[15];

  const int* src = eidx;
  const int* dst = eidx + E;

  size_t off = 0;
  auto alloc = [&](size_t bytes) -> void* {
    void* p = (char*)d_ws + off;
    off += (bytes + 255) & ~(size_t)255;
    return p;
  };
  int*    degi   = (int*)alloc((size_t)N * 4);
  float*  alps   = (float*)alloc((size_t)N * 4);
  float*  alpd   = (float*)alloc((size_t)N * 4);
  int*    eslot  = (int*)alloc((size_t)E * 4);
  int*    rowptr = (int*)alloc((size_t)(N + 1) * 4);
  float2* edgeD  = (float2*)alloc((size_t)E * 8);
  float4* csr    = (float4*)alloc((size_t)E * 16);
  unsigned short* W1t = (unsigned short*)alloc((size_t)128 * 256 * 2);
  unsigned short* W2t = (unsigned short*)alloc((size_t)128 * 128 * 2);
  unsigned short* hA  = (unsigned short*)alloc((size_t)N * H * 2);
  unsigned short* hB  = (unsigned short*)alloc((size_t)N * H * 2);

  hipMemsetAsync(degi, 0, (size_t)N * 4, stream);

  int CB = (E + 255) / 256;                  // atomic-count blocks (3125)
  int EDOTB = 3125;                          // 3125 blocks x 64 qg x 4 passes = 800K edges
  // ---- mega-prep: e-dot stream + count atomics + W transposes ----
  k_prep<<<EDOTB + CB + 192, 256, 0, stream>>>(dst, degi, eslot, E, EDOTB, CB,
                                               We1, ae1, We2, ae2, ef, edgeD,
                                               W1, W1t, W2, W2t);
  k_scan<<<1, 1024, 0, stream>>>(degi, rowptr, N, E);

  int gwaves = (N + 15) / 16;                // full-width waves
  int GB = (gwaves + 3) / 4;
  int SB = (E + 255) / 256;
  // ---- layer 1 GEMM (+alpha) overlapped with CSR scatter ----
  k_scatgemm<<<GB + SB, 256, 0, stream>>>(src, dst, eslot, rowptr, edgeD, csr, E, GB,
                                          x, W1t, hA, as1, ad1, alps, alpd, N);
  k_agg<<<(N + 3) / 4, 256, 0, stream>>>(rowptr, csr, alps, alpd, hA, b1, hB, N, 0, 1);
  // ---- layer 2 ----
  k_gemm<128, false><<<GB, 256, 0, stream>>>(hB, W2t, hA, as2, ad2, alps, alpd, N);
  k_agg<<<(N + 3) / 4, 256, 0, stream>>>(rowptr, csr, alps, alpd, hA, b2, hB, N, 1, 0);
  // ---- decode ----
  int dwaves = (half + 3) / 4;
  k_decode<<<(dwaves + 3) / 4, 256, 0, stream>>>(src, dst, hB, (float*)d_out, half);
}